// Round 3
// baseline (687.225 us; speedup 1.0000x reference)
//
#include <hip/hip_runtime.h>

#define B_  8
#define IB_ 1024
#define S_  4096
#define D_  512

typedef _Float16 f16;
typedef _Float16 f16x8 __attribute__((ext_vector_type(8)));
typedef _Float16 f16x4 __attribute__((ext_vector_type(4)));
typedef float    f32x4 __attribute__((ext_vector_type(4)));

// ---------------- async global->LDS, 16B per lane ----------------
__device__ __forceinline__ void gld_lds16(const f16* g, f16* l) {
  __builtin_amdgcn_global_load_lds(
      (const __attribute__((address_space(1))) void*)g,
      (__attribute__((address_space(3))) void*)l, 16, 0, 0);
}

// ---------------- generic C = A(M,K) * B(N,K)^T  (f16 in, f32 accum) -------
// 128x128 tile, BK=32, 256 threads = 4 waves (2x2), per-wave 64x64 via
// 4x4 x mfma_f32_16x16x32_f16. LDS linear (global_load_lds), source-side
// XOR swizzle (chunk ^= (row>>1)&3) so ds_read_b128 is ~2-way conflict-free.
// lda/ldb = element row strides. ksplit>1: grid.z = batch*ksplit, each slice
// computes K/ksplit and atomicAdds into pre-zeroed C32 (no bias allowed).
__global__ __launch_bounds__(256) void gemm_bt(
    const f16* __restrict__ A, const f16* __restrict__ B,
    float* __restrict__ C32, f16* __restrict__ C16,
    int M, int N, int K, int lda, int ldb, int ksplit,
    long long sAb, long long sBb, long long sCb,
    const float* __restrict__ bias_row, const float* __restrict__ bias_col,
    float scale)
{
  __shared__ f16 ldsA[128 * 32];
  __shared__ f16 ldsB[128 * 32];
  const int tid  = threadIdx.x;
  const int lane = tid & 63;
  const int wave = tid >> 6;
  const int zb   = blockIdx.z / ksplit;
  const int ks   = blockIdx.z % ksplit;
  A += (size_t)zb * (size_t)sAb;
  B += (size_t)zb * (size_t)sBb;
  const int m0 = blockIdx.y * 128;
  const int n0 = blockIdx.x * 128;
  const int wm = wave >> 1, wn = wave & 1;

  f32x4 acc[4][4];
#pragma unroll
  for (int i = 0; i < 4; ++i)
#pragma unroll
    for (int j = 0; j < 4; ++j) acc[i][j] = (f32x4){0.f, 0.f, 0.f, 0.f};

  // per-lane fragment LDS element offsets (swizzled)
  int aoff[4], boff[4];
  const int cl = lane >> 4;
#pragma unroll
  for (int r = 0; r < 4; ++r) {
    int rowa = wm * 64 + r * 16 + (lane & 15);
    aoff[r] = rowa * 32 + (cl ^ ((rowa >> 1) & 3)) * 8;
    int rowb = wn * 64 + r * 16 + (lane & 15);
    boff[r] = rowb * 32 + (cl ^ ((rowb >> 1) & 3)) * 8;
  }
  // staging coords: 512 16B-chunks per tile, 2 per thread; physical chunk
  // (row,cp) holds global chunk cg = cp ^ ((row>>1)&3)
  int srow[2], scg[2];
#pragma unroll
  for (int it = 0; it < 2; ++it) {
    int ch = wave * 64 + it * 256 + lane;
    srow[it] = ch >> 2;
    scg[it]  = (ch & 3) ^ ((srow[it] >> 1) & 3);
  }

  const int Kc = K / ksplit;
  const int kbeg = ks * Kc;
  for (int k0 = kbeg; k0 < kbeg + Kc; k0 += 32) {
#pragma unroll
    for (int it = 0; it < 2; ++it) {
      gld_lds16(A + (size_t)(m0 + srow[it]) * (size_t)lda + (k0 + scg[it] * 8),
                &ldsA[(wave * 64 + it * 256) * 8]);
      gld_lds16(B + (size_t)(n0 + srow[it]) * (size_t)ldb + (k0 + scg[it] * 8),
                &ldsB[(wave * 64 + it * 256) * 8]);
    }
    __syncthreads();
    f16x8 af[4], bf[4];
#pragma unroll
    for (int r = 0; r < 4; ++r) af[r] = *(const f16x8*)&ldsA[aoff[r]];
#pragma unroll
    for (int r = 0; r < 4; ++r) bf[r] = *(const f16x8*)&ldsB[boff[r]];
#pragma unroll
    for (int mr = 0; mr < 4; ++mr)
#pragma unroll
      for (int nr = 0; nr < 4; ++nr)
        acc[mr][nr] = __builtin_amdgcn_mfma_f32_16x16x32_f16(
            af[mr], bf[nr], acc[mr][nr], 0, 0, 0);
    __syncthreads();
  }

  float* c32 = C32 ? C32 + (size_t)zb * (size_t)sCb : nullptr;
  f16*   c16 = C16 ? C16 + (size_t)zb * (size_t)sCb : nullptr;
  // C/D layout [m89]: col = lane&15, row = (lane>>4)*4 + reg
#pragma unroll
  for (int mr = 0; mr < 4; ++mr) {
#pragma unroll
    for (int r = 0; r < 4; ++r) {
      int grow = m0 + wm * 64 + mr * 16 + (lane >> 4) * 4 + r;
      float brv = bias_row ? bias_row[grow] : 0.f;
#pragma unroll
      for (int nr = 0; nr < 4; ++nr) {
        int gcol = n0 + wn * 64 + nr * 16 + (lane & 15);
        float v = acc[mr][nr][r] * scale + brv +
                  (bias_col ? bias_col[gcol] : 0.f);
        if (ksplit > 1)      atomicAdd(&c32[(size_t)grow * N + gcol], v);
        else if (c32)        c32[(size_t)grow * N + gcol] = v;
        else                 c16[(size_t)grow * N + gcol] = (f16)v;
      }
    }
  }
}

// ---------------- f32 -> f16 ----------------
__global__ __launch_bounds__(256) void cvt_f32_to_f16(
    const float* __restrict__ in, f16* __restrict__ out, unsigned n)
{
  unsigned i = (blockIdx.x * 256u + threadIdx.x) * 4u;
  if (i >= n) return;
  const float4 v = *(const float4*)(in + i);
  f16x4 h;
  h[0] = (f16)v.x; h[1] = (f16)v.y; h[2] = (f16)v.z; h[3] = (f16)v.w;
  *(f16x4*)(out + i) = h;
}

// ---------------- zero-fill f32 buffer (float4 grid-stride) --------------
__global__ __launch_bounds__(256) void fill_zero4(float4* __restrict__ p,
                                                  unsigned n4)
{
  unsigned i = blockIdx.x * 256u + threadIdx.x;
  unsigned stride = gridDim.x * 256u;
  const float4 z = {0.f, 0.f, 0.f, 0.f};
  for (; i < n4; i += stride) p[i] = z;
}

// ---------------- row sums of Wb2s (S, IB): A[s] = sum_j W[s,j] ----------
__global__ __launch_bounds__(256) void rowsum_kernel(
    const float* __restrict__ W, float* __restrict__ out)
{
  int s = blockIdx.x;
  const float* row = W + (size_t)s * IB_;
  float acc = 0.f;
  for (int j = threadIdx.x; j < IB_; j += 256) acc += row[j];
  __shared__ float red[4];
#pragma unroll
  for (int o = 32; o >= 1; o >>= 1) acc += __shfl_xor(acc, o);
  if ((threadIdx.x & 63) == 0) red[threadIdx.x >> 6] = acc;
  __syncthreads();
  if (threadIdx.x == 0) out[s] = red[0] + red[1] + red[2] + red[3];
}

// ---------------- transpose Wb2s (S, IB) -> WT (IB, S), f32 --------------
__global__ __launch_bounds__(256) void transpose_f32(
    const float* __restrict__ in, float* __restrict__ out)
{
  __shared__ float t[32][33];
  int c0 = blockIdx.x * 32;          // col in 'in' (j)
  int r0 = blockIdx.y * 32;          // row in 'in' (s)
  int tx = threadIdx.x & 31, ty = threadIdx.x >> 5;
  for (int j = ty; j < 32; j += 8)
    t[j][tx] = in[(size_t)(r0 + j) * IB_ + c0 + tx];
  __syncthreads();
  for (int j = ty; j < 32; j += 8)
    out[(size_t)(c0 + j) * S_ + r0 + tx] = t[tx][j];
}

// ---------------- banded-softmax row + top-k(2050) -> sparse f16 ---------
__device__ __forceinline__ unsigned fkey(float x) {
  unsigned u = __float_as_uint(x);
  return (u & 0x80000000u) ? ~u : (u | 0x80000000u);
}

__global__ __launch_bounds__(256) void sparse_topk(
    const float* __restrict__ WT, const float* __restrict__ Acs,
    const float* __restrict__ bb2s, f16* __restrict__ sp)
{
  const int i = blockIdx.x;   // 0..IB-1
  __shared__ float vals[S_];
  __shared__ unsigned hist[256];
  __shared__ unsigned sprefix;
  __shared__ int srem;
  const float e1 = 2.71828182845904523536f;
  const int n1 = (i == 0 || i == IB_ - 1) ? 2 : 3;
  const float Z = (float)n1 * e1 + (float)(IB_ - n1);
  const float alpha = 1.f / Z;
  const float beta  = (e1 - 1.f) / Z;
  const float* wmid = WT + (size_t)i * S_;
  const float* wlo  = (i > 0)       ? WT + (size_t)(i - 1) * S_ : nullptr;
  const float* whi  = (i < IB_ - 1) ? WT + (size_t)(i + 1) * S_ : nullptr;
  for (int s = threadIdx.x; s < S_; s += 256) {
    float band = wmid[s];
    if (wlo) band += wlo[s];
    if (whi) band += whi[s];
    vals[s] = alpha * Acs[s] + beta * band + bb2s[s];
  }
  if (threadIdx.x == 0) { sprefix = 0u; srem = S_ / 2 + 2; }  // 2050
  __syncthreads();
  for (int shift = 24; shift >= 0; shift -= 8) {
    hist[threadIdx.x] = 0u;
    __syncthreads();
    unsigned pfx = sprefix;
    unsigned himask = (shift == 24) ? 0u : (0xFFFFFFFFu << (shift + 8));
    for (int s = threadIdx.x; s < S_; s += 256) {
      unsigned key = fkey(vals[s]);
      if ((key & himask) == (pfx & himask))
        atomicAdd(&hist[(key >> shift) & 255u], 1u);
    }
    __syncthreads();
    if (threadIdx.x == 0) {
      int rem = srem;
      unsigned acc = 0;
      int b = 255;
      for (; b > 0; --b) {
        unsigned c = hist[b];
        if (acc + c >= (unsigned)rem) break;
        acc += c;
      }
      sprefix = pfx | ((unsigned)b << shift);
      srem = rem - (int)acc;
    }
    __syncthreads();
  }
  const unsigned T = sprefix;
  for (int s = threadIdx.x; s < S_; s += 256) {
    float v = vals[s];
    sp[(size_t)i * S_ + s] = (fkey(v) >= T) ? (f16)v : (f16)0.f;
  }
}

// ---------------- in-place row softmax over f16 rows of length S ---------
__global__ __launch_bounds__(256) void softmax_rows_f16(f16* __restrict__ L)
{
  f16* row = L + (size_t)blockIdx.x * S_;
  const int t = threadIdx.x;
  __shared__ float red[4];
  f16x8 a = *(const f16x8*)(row + t * 8);
  f16x8 b = *(const f16x8*)(row + 2048 + t * 8);
  float v[16];
#pragma unroll
  for (int j = 0; j < 8; ++j) { v[j] = (float)a[j]; v[8 + j] = (float)b[j]; }
  float mx = -3.4e38f;
#pragma unroll
  for (int j = 0; j < 16; ++j) mx = fmaxf(mx, v[j]);
#pragma unroll
  for (int o = 32; o >= 1; o >>= 1) mx = fmaxf(mx, __shfl_xor(mx, o));
  if ((t & 63) == 0) red[t >> 6] = mx;
  __syncthreads();
  mx = fmaxf(fmaxf(red[0], red[1]), fmaxf(red[2], red[3]));
  __syncthreads();
  float sum = 0.f;
#pragma unroll
  for (int j = 0; j < 16; ++j) { v[j] = __expf(v[j] - mx); sum += v[j]; }
#pragma unroll
  for (int o = 32; o >= 1; o >>= 1) sum += __shfl_xor(sum, o);
  if ((t & 63) == 0) red[t >> 6] = sum;
  __syncthreads();
  sum = red[0] + red[1] + red[2] + red[3];
  const float inv = 1.f / sum;
#pragma unroll
  for (int j = 0; j < 8; ++j) {
    a[j] = (f16)(v[j] * inv); b[j] = (f16)(v[8 + j] * inv);
  }
  *(f16x8*)(row + t * 8) = a;
  *(f16x8*)(row + 2048 + t * 8) = b;
}

// =========================================================================
extern "C" void kernel_launch(void* const* d_in, const int* in_sizes, int n_in,
                              void* d_out, int out_size, void* d_ws, size_t ws_size,
                              hipStream_t stream)
{
  const float* text = (const float*)d_in[0];   // (B,S,D)
  const float* img  = (const float*)d_in[1];   // (B,IB,D)
  const float* Wq   = (const float*)d_in[2];
  const float* bq   = (const float*)d_in[3];
  const float* Wk   = (const float*)d_in[4];
  const float* bk   = (const float*)d_in[5];
  const float* Wv   = (const float*)d_in[6];
  const float* bv   = (const float*)d_in[7];
  const float* Wb2s = (const float*)d_in[8];   // (S,IB)
  const float* bb2s = (const float*)d_in[9];   // (S,)
  float* outp = (float*)d_out;
  char* ws = (char*)d_ws;

  const long long SD = (long long)S_ * D_;
  const long long DS = (long long)D_ * S_;
  const long long DI = (long long)D_ * IB_;
  const long long IS = (long long)IB_ * S_;
  const long long ID = (long long)IB_ * D_;
  const size_t MB = 1048576ull;

  // layout (round-2 profile proved ws >= 200 MiB; NEED = ~162.1 MiB):
  //  [  0, 64)  text16[cvt->5) 0-32 | kT[4->6) 32-64 | logits16[8->10) 0-64
  //  [ 64, 96)  vT   [5->10)
  //  [ 96,104)  qb   [3->8)
  //  [104,136)  Nb   [7->8)
  //  [136,152)  WTf  [tr->topk) -> MT32 [6->6b)
  //  [152,160)  img16[cvt->3)  -> MT16 [6b->7)
  //  [160,...)  wq16|wk16|wv16 (1.5M), Acs (16K)
  // d_out (16M): sparse [topk->6) 0-8 | W16 [cvt->7) 8-16; zero-filled after 7.
  const size_t NEED = 162 * MB + 16384;
  if (ws_size < NEED) return;

  f16*   text16 = (f16*)(ws + 0);
  f16*   kT     = (f16*)(ws + 32 * MB);
  f16*   logits = (f16*)(ws + 0);
  f16*   vT     = (f16*)(ws + 64 * MB);
  f16*   qb     = (f16*)(ws + 96 * MB);
  f16*   Nb     = (f16*)(ws + 104 * MB);
  float* WTf    = (float*)(ws + 136 * MB);
  float* MT32   = (float*)(ws + 136 * MB);
  f16*   img16  = (f16*)(ws + 152 * MB);
  f16*   MT16   = (f16*)(ws + 152 * MB);
  f16*   wq16   = (f16*)(ws + 160 * MB);
  f16*   wk16   = wq16 + 262144;
  f16*   wv16   = wk16 + 262144;
  float* Acs    = (float*)(ws + 161 * MB + 524288);
  f16*   sparse = (f16*)d_out;
  f16*   W16    = (f16*)((char*)d_out + 8 * MB);

  dim3 blk(256);
  const float scl = 0.04419417382415922f;  // 1/sqrt(512)
  const int KS = 4;                        // split-K factor for K=4096 GEMMs

  // 1) f32 -> f16 conversions
  cvt_f32_to_f16<<<(B_*S_*D_)/1024, blk, 0, stream>>>(text, text16, B_*S_*D_);
  cvt_f32_to_f16<<<(B_*IB_*D_)/1024, blk, 0, stream>>>(img, img16, B_*IB_*D_);
  cvt_f32_to_f16<<<(D_*D_)/1024, blk, 0, stream>>>(Wq, wq16, D_*D_);
  cvt_f32_to_f16<<<(D_*D_)/1024, blk, 0, stream>>>(Wk, wk16, D_*D_);
  cvt_f32_to_f16<<<(D_*D_)/1024, blk, 0, stream>>>(Wv, wv16, D_*D_);
  cvt_f32_to_f16<<<(S_*IB_)/1024, blk, 0, stream>>>(Wb2s, W16, S_*IB_);

  // 2) batch-invariant sparse pattern
  rowsum_kernel<<<S_, blk, 0, stream>>>(Wb2s, Acs);
  transpose_f32<<<dim3(IB_/32, S_/32), blk, 0, stream>>>(Wb2s, WTf);
  sparse_topk<<<IB_, blk, 0, stream>>>(WTf, Acs, bb2s, sparse);

  // 3) q = img @ Wq^T + bq : (B*IB, D) f16, batch folded into M
  gemm_bt<<<dim3(D_/128, (B_*IB_)/128, 1), blk, 0, stream>>>(
      img16, wq16, nullptr, qb, B_*IB_, D_, D_, D_, D_, 1,
      0, 0, 0, nullptr, bq, 1.f);
  // 4) kT_b = Wk @ text_b^T + bk : (D, S) x B
  gemm_bt<<<dim3(S_/128, D_/128, B_), blk, 0, stream>>>(
      wk16, text16, nullptr, kT, D_, S_, D_, D_, D_, 1,
      0, SD, DS, bk, nullptr, 1.f);
  // 5) vT_b = Wv @ text_b^T + bv
  gemm_bt<<<dim3(S_/128, D_/128, B_), blk, 0, stream>>>(
      wv16, text16, nullptr, vT, D_, S_, D_, D_, D_, 1,
      0, SD, DS, bv, nullptr, 1.f);
  // 6) MT_b = kT_b @ sparse^T : (D, IB) x B, split-K=4 atomic f32
  fill_zero4<<<1024, blk, 0, stream>>>((float4*)MT32, (B_*DI) / 4);
  gemm_bt<<<dim3(IB_/128, D_/128, B_*KS), blk, 0, stream>>>(
      kT, sparse, MT32, nullptr, D_, IB_, S_, S_, S_, KS,
      DS, 0, DI, nullptr, nullptr, 1.f);
  // 6b) MT32 -> MT16
  cvt_f32_to_f16<<<(B_*D_*IB_)/1024, blk, 0, stream>>>(MT32, MT16, B_*D_*IB_);
  // 7) N_b = Wb2s @ MT_b^T : (S, D) x B
  gemm_bt<<<dim3(D_/128, S_/128, B_), blk, 0, stream>>>(
      W16, MT16, nullptr, Nb, S_, D_, IB_, IB_, IB_, 1,
      0, DI, SD, nullptr, nullptr, 1.f);
  // d_out scratch (sparse, W16) now dead -> zero for the PV atomics
  fill_zero4<<<1024, blk, 0, stream>>>((float4*)outp, (B_*ID) / 4);
  // 8) logits_b = q_b @ N_b^T * scl + bb2s : (IB, S) f16 x B
  gemm_bt<<<dim3(S_/128, IB_/128, B_), blk, 0, stream>>>(
      qb, Nb, nullptr, logits, IB_, S_, D_, D_, D_, 1,
      ID, SD, IS, nullptr, bb2s, scl);
  // 9) row softmax, in place on f16 rows
  softmax_rows_f16<<<B_*IB_, blk, 0, stream>>>(logits);
  // 10) out_b = P_b @ vT_b^T : (IB, D) f32 x B, split-K=4 atomic into d_out
  gemm_bt<<<dim3(D_/128, IB_/128, B_*KS), blk, 0, stream>>>(
      logits, vT, outp, nullptr, IB_, D_, S_, S_, S_, KS,
      IS, DS, ID, nullptr, nullptr, 1.f);
}

// Round 4
// 572.488 us; speedup vs baseline: 1.2004x; 1.2004x over previous
//
#include <hip/hip_runtime.h>

#define B_  8
#define IB_ 1024
#define S_  4096
#define D_  512

typedef _Float16 f16;
typedef _Float16 f16x8 __attribute__((ext_vector_type(8)));
typedef _Float16 f16x4 __attribute__((ext_vector_type(4)));
typedef float    f32x4 __attribute__((ext_vector_type(4)));

// ---------------- async global->LDS, 16B per lane ----------------
__device__ __forceinline__ void gld_lds16(const f16* g, f16* l) {
  __builtin_amdgcn_global_load_lds(
      (const __attribute__((address_space(1))) void*)g,
      (__attribute__((address_space(3))) void*)l, 16, 0, 0);
}

// ---------------- generic C = A(M,K) * B(N,K)^T  (f16 in, f32 accum) -------
// 128x128 tile, BK=32, 256 threads = 4 waves (2x2), per-wave 64x64 via
// 4x4 x mfma_f32_16x16x32_f16. LDS linear (global_load_lds), source-side
// XOR swizzle (chunk ^= (row>>1)&3) so ds_read_b128 is ~2-way conflict-free.
// lda/ldb = element row strides. ksplit>1: grid.z = batch*ksplit (z=zb*KS+ks),
// each slice computes K/ksplit and PLAIN-STORES its partial to
// C32 + blockIdx.z*sCb (two-stage split-K; reducer sums slices afterwards).
__global__ __launch_bounds__(256) void gemm_bt(
    const f16* __restrict__ A, const f16* __restrict__ B,
    float* __restrict__ C32, f16* __restrict__ C16,
    int M, int N, int K, int lda, int ldb, int ksplit,
    long long sAb, long long sBb, long long sCb,
    const float* __restrict__ bias_row, const float* __restrict__ bias_col,
    float scale)
{
  __shared__ f16 ldsA[128 * 32];
  __shared__ f16 ldsB[128 * 32];
  const int tid  = threadIdx.x;
  const int lane = tid & 63;
  const int wave = tid >> 6;
  const int zb   = blockIdx.z / ksplit;
  const int ks   = blockIdx.z % ksplit;
  A += (size_t)zb * (size_t)sAb;
  B += (size_t)zb * (size_t)sBb;
  const int m0 = blockIdx.y * 128;
  const int n0 = blockIdx.x * 128;
  const int wm = wave >> 1, wn = wave & 1;

  f32x4 acc[4][4];
#pragma unroll
  for (int i = 0; i < 4; ++i)
#pragma unroll
    for (int j = 0; j < 4; ++j) acc[i][j] = (f32x4){0.f, 0.f, 0.f, 0.f};

  // per-lane fragment LDS element offsets (swizzled)
  int aoff[4], boff[4];
  const int cl = lane >> 4;
#pragma unroll
  for (int r = 0; r < 4; ++r) {
    int rowa = wm * 64 + r * 16 + (lane & 15);
    aoff[r] = rowa * 32 + (cl ^ ((rowa >> 1) & 3)) * 8;
    int rowb = wn * 64 + r * 16 + (lane & 15);
    boff[r] = rowb * 32 + (cl ^ ((rowb >> 1) & 3)) * 8;
  }
  // staging coords: 512 16B-chunks per tile, 2 per thread; physical chunk
  // (row,cp) holds global chunk cg = cp ^ ((row>>1)&3)
  int srow[2], scg[2];
#pragma unroll
  for (int it = 0; it < 2; ++it) {
    int ch = wave * 64 + it * 256 + lane;
    srow[it] = ch >> 2;
    scg[it]  = (ch & 3) ^ ((srow[it] >> 1) & 3);
  }

  const int Kc = K / ksplit;
  const int kbeg = ks * Kc;
  for (int k0 = kbeg; k0 < kbeg + Kc; k0 += 32) {
#pragma unroll
    for (int it = 0; it < 2; ++it) {
      gld_lds16(A + (size_t)(m0 + srow[it]) * (size_t)lda + (k0 + scg[it] * 8),
                &ldsA[(wave * 64 + it * 256) * 8]);
      gld_lds16(B + (size_t)(n0 + srow[it]) * (size_t)ldb + (k0 + scg[it] * 8),
                &ldsB[(wave * 64 + it * 256) * 8]);
    }
    __syncthreads();
    f16x8 af[4], bf[4];
#pragma unroll
    for (int r = 0; r < 4; ++r) af[r] = *(const f16x8*)&ldsA[aoff[r]];
#pragma unroll
    for (int r = 0; r < 4; ++r) bf[r] = *(const f16x8*)&ldsB[boff[r]];
#pragma unroll
    for (int mr = 0; mr < 4; ++mr)
#pragma unroll
      for (int nr = 0; nr < 4; ++nr)
        acc[mr][nr] = __builtin_amdgcn_mfma_f32_16x16x32_f16(
            af[mr], bf[nr], acc[mr][nr], 0, 0, 0);
    __syncthreads();
  }

  const size_t cz = (ksplit > 1) ? (size_t)blockIdx.z : (size_t)zb;
  float* c32 = C32 ? C32 + cz * (size_t)sCb : nullptr;
  f16*   c16 = C16 ? C16 + cz * (size_t)sCb : nullptr;
  // C/D layout [m89]: col = lane&15, row = (lane>>4)*4 + reg
#pragma unroll
  for (int mr = 0; mr < 4; ++mr) {
#pragma unroll
    for (int r = 0; r < 4; ++r) {
      int grow = m0 + wm * 64 + mr * 16 + (lane >> 4) * 4 + r;
      float brv = bias_row ? bias_row[grow] : 0.f;
#pragma unroll
      for (int nr = 0; nr < 4; ++nr) {
        int gcol = n0 + wn * 64 + nr * 16 + (lane & 15);
        float v = acc[mr][nr][r] * scale + brv +
                  (bias_col ? bias_col[gcol] : 0.f);
        if (c32) c32[(size_t)grow * N + gcol] = v;
        else     c16[(size_t)grow * N + gcol] = (f16)v;
      }
    }
  }
}

// ---------------- reduce 4 split-K partial slices -------------------------
// Partials p laid out as [batch][4][2^19] f32. Output flat [batch][2^19],
// f32 (o32) or f16 (o16). n4 = total output elems / 4.
__global__ __launch_bounds__(256) void reduce_ks4(
    const float4* __restrict__ p, float4* __restrict__ o32,
    f16* __restrict__ o16, unsigned n4)
{
  const unsigned pb4 = (1u << 19) / 4;  // per-batch float4 count
  unsigned i = blockIdx.x * 256u + threadIdx.x;
  const unsigned stride = gridDim.x * 256u;
  for (; i < n4; i += stride) {
    unsigned g = i / pb4, r = i - g * pb4;
    size_t base = ((size_t)g * 4u) * pb4 + r;
    float4 a = p[base];
    float4 b = p[base + pb4];
    float4 c = p[base + 2u * pb4];
    float4 d = p[base + 3u * pb4];
    float4 s = {a.x + b.x + c.x + d.x, a.y + b.y + c.y + d.y,
                a.z + b.z + c.z + d.z, a.w + b.w + c.w + d.w};
    if (o32) o32[i] = s;
    else {
      f16x4 h; h[0] = (f16)s.x; h[1] = (f16)s.y;
      h[2] = (f16)s.z; h[3] = (f16)s.w;
      *(f16x4*)(o16 + (size_t)i * 4) = h;
    }
  }
}

// ---------------- f32 -> f16 ----------------
__global__ __launch_bounds__(256) void cvt_f32_to_f16(
    const float* __restrict__ in, f16* __restrict__ out, unsigned n)
{
  unsigned i = (blockIdx.x * 256u + threadIdx.x) * 4u;
  if (i >= n) return;
  const float4 v = *(const float4*)(in + i);
  f16x4 h;
  h[0] = (f16)v.x; h[1] = (f16)v.y; h[2] = (f16)v.z; h[3] = (f16)v.w;
  *(f16x4*)(out + i) = h;
}

// ---------------- row sums of Wb2s (S, IB): A[s] = sum_j W[s,j] ----------
__global__ __launch_bounds__(256) void rowsum_kernel(
    const float* __restrict__ W, float* __restrict__ out)
{
  int s = blockIdx.x;
  const float* row = W + (size_t)s * IB_;
  float acc = 0.f;
  for (int j = threadIdx.x; j < IB_; j += 256) acc += row[j];
  __shared__ float red[4];
#pragma unroll
  for (int o = 32; o >= 1; o >>= 1) acc += __shfl_xor(acc, o);
  if ((threadIdx.x & 63) == 0) red[threadIdx.x >> 6] = acc;
  __syncthreads();
  if (threadIdx.x == 0) out[s] = red[0] + red[1] + red[2] + red[3];
}

// ---------------- transpose Wb2s (S, IB) -> WT (IB, S), f32 --------------
__global__ __launch_bounds__(256) void transpose_f32(
    const float* __restrict__ in, float* __restrict__ out)
{
  __shared__ float t[32][33];
  int c0 = blockIdx.x * 32;          // col in 'in' (j)
  int r0 = blockIdx.y * 32;          // row in 'in' (s)
  int tx = threadIdx.x & 31, ty = threadIdx.x >> 5;
  for (int j = ty; j < 32; j += 8)
    t[j][tx] = in[(size_t)(r0 + j) * IB_ + c0 + tx];
  __syncthreads();
  for (int j = ty; j < 32; j += 8)
    out[(size_t)(c0 + j) * S_ + r0 + tx] = t[tx][j];
}

// ---------------- banded-softmax row + top-k(2050) -> sparse f16 ---------
__device__ __forceinline__ unsigned fkey(float x) {
  unsigned u = __float_as_uint(x);
  return (u & 0x80000000u) ? ~u : (u | 0x80000000u);
}

__global__ __launch_bounds__(256) void sparse_topk(
    const float* __restrict__ WT, const float* __restrict__ Acs,
    const float* __restrict__ bb2s, f16* __restrict__ sp)
{
  const int i = blockIdx.x;   // 0..IB-1
  __shared__ float vals[S_];
  __shared__ unsigned hist[256];
  __shared__ unsigned sprefix;
  __shared__ int srem;
  const float e1 = 2.71828182845904523536f;
  const int n1 = (i == 0 || i == IB_ - 1) ? 2 : 3;
  const float Z = (float)n1 * e1 + (float)(IB_ - n1);
  const float alpha = 1.f / Z;
  const float beta  = (e1 - 1.f) / Z;
  const float* wmid = WT + (size_t)i * S_;
  const float* wlo  = (i > 0)       ? WT + (size_t)(i - 1) * S_ : nullptr;
  const float* whi  = (i < IB_ - 1) ? WT + (size_t)(i + 1) * S_ : nullptr;
  for (int s = threadIdx.x; s < S_; s += 256) {
    float band = wmid[s];
    if (wlo) band += wlo[s];
    if (whi) band += whi[s];
    vals[s] = alpha * Acs[s] + beta * band + bb2s[s];
  }
  if (threadIdx.x == 0) { sprefix = 0u; srem = S_ / 2 + 2; }  // 2050
  __syncthreads();
  for (int shift = 24; shift >= 0; shift -= 8) {
    hist[threadIdx.x] = 0u;
    __syncthreads();
    unsigned pfx = sprefix;
    unsigned himask = (shift == 24) ? 0u : (0xFFFFFFFFu << (shift + 8));
    for (int s = threadIdx.x; s < S_; s += 256) {
      unsigned key = fkey(vals[s]);
      if ((key & himask) == (pfx & himask))
        atomicAdd(&hist[(key >> shift) & 255u], 1u);
    }
    __syncthreads();
    if (threadIdx.x == 0) {
      int rem = srem;
      unsigned acc = 0;
      int b = 255;
      for (; b > 0; --b) {
        unsigned c = hist[b];
        if (acc + c >= (unsigned)rem) break;
        acc += c;
      }
      sprefix = pfx | ((unsigned)b << shift);
      srem = rem - (int)acc;
    }
    __syncthreads();
  }
  const unsigned T = sprefix;
  for (int s = threadIdx.x; s < S_; s += 256) {
    float v = vals[s];
    sp[(size_t)i * S_ + s] = (fkey(v) >= T) ? (f16)v : (f16)0.f;
  }
}

// ---------------- in-place row softmax over f16 rows of length S ---------
__global__ __launch_bounds__(256) void softmax_rows_f16(f16* __restrict__ L)
{
  f16* row = L + (size_t)blockIdx.x * S_;
  const int t = threadIdx.x;
  __shared__ float red[4];
  f16x8 a = *(const f16x8*)(row + t * 8);
  f16x8 b = *(const f16x8*)(row + 2048 + t * 8);
  float v[16];
#pragma unroll
  for (int j = 0; j < 8; ++j) { v[j] = (float)a[j]; v[8 + j] = (float)b[j]; }
  float mx = -3.4e38f;
#pragma unroll
  for (int j = 0; j < 16; ++j) mx = fmaxf(mx, v[j]);
#pragma unroll
  for (int o = 32; o >= 1; o >>= 1) mx = fmaxf(mx, __shfl_xor(mx, o));
  if ((t & 63) == 0) red[t >> 6] = mx;
  __syncthreads();
  mx = fmaxf(fmaxf(red[0], red[1]), fmaxf(red[2], red[3]));
  __syncthreads();
  float sum = 0.f;
#pragma unroll
  for (int j = 0; j < 16; ++j) { v[j] = __expf(v[j] - mx); sum += v[j]; }
#pragma unroll
  for (int o = 32; o >= 1; o >>= 1) sum += __shfl_xor(sum, o);
  if ((t & 63) == 0) red[t >> 6] = sum;
  __syncthreads();
  sum = red[0] + red[1] + red[2] + red[3];
  const float inv = 1.f / sum;
#pragma unroll
  for (int j = 0; j < 8; ++j) {
    a[j] = (f16)(v[j] * inv); b[j] = (f16)(v[8 + j] * inv);
  }
  *(f16x8*)(row + t * 8) = a;
  *(f16x8*)(row + 2048 + t * 8) = b;
}

// =========================================================================
extern "C" void kernel_launch(void* const* d_in, const int* in_sizes, int n_in,
                              void* d_out, int out_size, void* d_ws, size_t ws_size,
                              hipStream_t stream)
{
  const float* text = (const float*)d_in[0];   // (B,S,D)
  const float* img  = (const float*)d_in[1];   // (B,IB,D)
  const float* Wq   = (const float*)d_in[2];
  const float* bq   = (const float*)d_in[3];
  const float* Wk   = (const float*)d_in[4];
  const float* bk   = (const float*)d_in[5];
  const float* Wv   = (const float*)d_in[6];
  const float* bv   = (const float*)d_in[7];
  const float* Wb2s = (const float*)d_in[8];   // (S,IB)
  const float* bb2s = (const float*)d_in[9];   // (S,)
  float* outp = (float*)d_out;
  char* ws = (char*)d_ws;

  const long long SD = (long long)S_ * D_;
  const long long DS = (long long)D_ * S_;
  const long long DI = (long long)D_ * IB_;    // 2^19
  const long long IS = (long long)IB_ * S_;
  const long long ID = (long long)IB_ * D_;    // 2^19
  const size_t MB = 1048576ull;

  // layout (ws >= 200 MiB proved in round 2; NEED = 200 MiB):
  //  [  0, 64)  text16[cvt->5) 0-32 | kT[4->6) 32-64 | logits16[8->10) 0-64
  //  [ 64, 96)  vT   [5->10)
  //  [ 96,104)  qb   [3->8)
  //  [104,136)  Nb   [7->8)
  //  [136,200)  WTf[tr->topk) | img16 | w*16 | Acs   (all dead by step 6)
  //             -> MT partials [6 ->6b) -> PV partials [10 ->10b)
  // d_out (16M): sparse[topk->6) 0-8 -> MT16[6b->7) | W16[cvt->7) 8-16;
  //              final PV reduce overwrites d_out at 10b.
  const size_t NEED = 200 * MB;
  if (ws_size < NEED) return;

  f16*   text16 = (f16*)(ws + 0);
  f16*   kT     = (f16*)(ws + 32 * MB);
  f16*   logits = (f16*)(ws + 0);
  f16*   vT     = (f16*)(ws + 64 * MB);
  f16*   qb     = (f16*)(ws + 96 * MB);
  f16*   Nb     = (f16*)(ws + 104 * MB);
  float* WTf    = (float*)(ws + 136 * MB);
  f16*   img16  = (f16*)(ws + 152 * MB);
  f16*   wq16   = (f16*)(ws + 160 * MB);
  f16*   wk16   = wq16 + 262144;
  f16*   wv16   = wk16 + 262144;
  float* Acs    = (float*)(ws + 161 * MB + 524288);
  float* parts  = (float*)(ws + 136 * MB);     // 64 MB split-K partials
  f16*   sparse = (f16*)d_out;
  f16*   MT16   = (f16*)d_out;                 // after sparse dies (step 6)
  f16*   W16    = (f16*)((char*)d_out + 8 * MB);

  dim3 blk(256);
  const float scl = 0.04419417382415922f;  // 1/sqrt(512)
  const int KS = 4;                        // split-K factor for K=4096 GEMMs

  // 1) f32 -> f16 conversions
  cvt_f32_to_f16<<<(B_*S_*D_)/1024, blk, 0, stream>>>(text, text16, B_*S_*D_);
  cvt_f32_to_f16<<<(B_*IB_*D_)/1024, blk, 0, stream>>>(img, img16, B_*IB_*D_);
  cvt_f32_to_f16<<<(D_*D_)/1024, blk, 0, stream>>>(Wq, wq16, D_*D_);
  cvt_f32_to_f16<<<(D_*D_)/1024, blk, 0, stream>>>(Wk, wk16, D_*D_);
  cvt_f32_to_f16<<<(D_*D_)/1024, blk, 0, stream>>>(Wv, wv16, D_*D_);
  cvt_f32_to_f16<<<(S_*IB_)/1024, blk, 0, stream>>>(Wb2s, W16, S_*IB_);

  // 2) batch-invariant sparse pattern
  rowsum_kernel<<<S_, blk, 0, stream>>>(Wb2s, Acs);
  transpose_f32<<<dim3(IB_/32, S_/32), blk, 0, stream>>>(Wb2s, WTf);
  sparse_topk<<<IB_, blk, 0, stream>>>(WTf, Acs, bb2s, sparse);

  // 3) q = img @ Wq^T + bq : (B*IB, D) f16, batch folded into M
  gemm_bt<<<dim3(D_/128, (B_*IB_)/128, 1), blk, 0, stream>>>(
      img16, wq16, nullptr, qb, B_*IB_, D_, D_, D_, D_, 1,
      0, 0, 0, nullptr, bq, 1.f);
  // 4) kT_b = Wk @ text_b^T + bk : (D, S) x B
  gemm_bt<<<dim3(S_/128, D_/128, B_), blk, 0, stream>>>(
      wk16, text16, nullptr, kT, D_, S_, D_, D_, D_, 1,
      0, SD, DS, bk, nullptr, 1.f);
  // 5) vT_b = Wv @ text_b^T + bv
  gemm_bt<<<dim3(S_/128, D_/128, B_), blk, 0, stream>>>(
      wv16, text16, nullptr, vT, D_, S_, D_, D_, D_, 1,
      0, SD, DS, bv, nullptr, 1.f);
  // 6) MT_b = kT_b @ sparse^T : (D, IB) x B, two-stage split-K=4
  gemm_bt<<<dim3(IB_/128, D_/128, B_*KS), blk, 0, stream>>>(
      kT, sparse, parts, nullptr, D_, IB_, S_, S_, S_, KS,
      DS, 0, DI, nullptr, nullptr, 1.f);
  // 6b) reduce partials -> MT16 f16 (into d_out; sparse is dead)
  reduce_ks4<<<2048, blk, 0, stream>>>(
      (const float4*)parts, nullptr, MT16, (unsigned)((B_*DI) / 4));
  // 7) N_b = Wb2s @ MT_b^T : (S, D) x B
  gemm_bt<<<dim3(D_/128, S_/128, B_), blk, 0, stream>>>(
      W16, MT16, nullptr, Nb, S_, D_, IB_, IB_, IB_, 1,
      0, DI, SD, nullptr, nullptr, 1.f);
  // 8) logits_b = q_b @ N_b^T * scl + bb2s : (IB, S) f16 x B
  gemm_bt<<<dim3(S_/128, IB_/128, B_), blk, 0, stream>>>(
      qb, Nb, nullptr, logits, IB_, S_, D_, D_, D_, 1,
      ID, SD, IS, nullptr, bb2s, scl);
  // 9) row softmax, in place on f16 rows
  softmax_rows_f16<<<B_*IB_, blk, 0, stream>>>(logits);
  // 10) out_b = P_b @ vT_b^T : (IB, D) x B, two-stage split-K=4
  gemm_bt<<<dim3(D_/128, IB_/128, B_*KS), blk, 0, stream>>>(
      logits, vT, parts, nullptr, IB_, D_, S_, S_, S_, KS,
      IS, DS, ID, nullptr, nullptr, 1.f);
  // 10b) reduce partials -> d_out f32
  reduce_ks4<<<2048, blk, 0, stream>>>(
      (const float4*)parts, (float4*)outp, nullptr, (unsigned)((B_*ID) / 4));
}

// Round 5
// 530.080 us; speedup vs baseline: 1.2965x; 1.0800x over previous
//
#include <hip/hip_runtime.h>

#define B_  8
#define IB_ 1024
#define S_  4096
#define D_  512

typedef _Float16 f16;
typedef _Float16 f16x8 __attribute__((ext_vector_type(8)));
typedef _Float16 f16x4 __attribute__((ext_vector_type(4)));
typedef float    f32x4 __attribute__((ext_vector_type(4)));

// ---------------- async global->LDS, 16B per lane ----------------
__device__ __forceinline__ void gld_lds16(const f16* g, f16* l) {
  __builtin_amdgcn_global_load_lds(
      (const __attribute__((address_space(1))) void*)g,
      (__attribute__((address_space(3))) void*)l, 16, 0, 0);
}

// ---------------- generic C = A(M,K) * B(N,K)^T  (f16 in, f32 accum) -------
// 128x128 tile, BK=32, 256 threads = 4 waves (2x2), per-wave 64x64 via
// 4x4 x mfma_f32_16x16x32_f16. Source-side XOR swizzle on staging so
// ds_read_b128 is ~conflict-free. 2-phase prefetch: double-buffered LDS,
// next tile's global_load_lds issued before current tile's MFMAs; raw
// s_barrier + counted vmcnt(4) so prefetch stays in flight across barriers
// (T3-minimum; hipcc's __syncthreads would drain vmcnt(0) - m97 ceiling).
// ksplit>1: grid.z = batch*ksplit, slice ks plain-stores partials to
// C32 + blockIdx.z*sCb (two-stage split-K; reduce_ks4 sums afterwards).
// epilogue: v = acc*scale + bias_row[m] + bias_col[n] + crossA[m]*crossB[n]
__global__ __launch_bounds__(256) void gemm_bt(
    const f16* __restrict__ A, const f16* __restrict__ B,
    float* __restrict__ C32, f16* __restrict__ C16,
    int M, int N, int K, int lda, int ldb, int ksplit,
    long long sAb, long long sBb, long long sCb,
    const float* __restrict__ bias_row, const float* __restrict__ bias_col,
    const float* __restrict__ crossA, const float* __restrict__ crossB,
    float scale)
{
  __shared__ f16 ldsA[2][128 * 32];
  __shared__ f16 ldsB[2][128 * 32];
  const int tid  = threadIdx.x;
  const int lane = tid & 63;
  const int wave = tid >> 6;
  const int zb   = blockIdx.z / ksplit;
  const int ks   = blockIdx.z % ksplit;
  A += (size_t)zb * (size_t)sAb;
  B += (size_t)zb * (size_t)sBb;
  const int m0 = blockIdx.y * 128;
  const int n0 = blockIdx.x * 128;
  const int wm = wave >> 1, wn = wave & 1;

  f32x4 acc[4][4];
#pragma unroll
  for (int i = 0; i < 4; ++i)
#pragma unroll
    for (int j = 0; j < 4; ++j) acc[i][j] = (f32x4){0.f, 0.f, 0.f, 0.f};

  // per-lane fragment LDS element offsets (swizzled)
  int aoff[4], boff[4];
  const int cl = lane >> 4;
#pragma unroll
  for (int r = 0; r < 4; ++r) {
    int rowa = wm * 64 + r * 16 + (lane & 15);
    aoff[r] = rowa * 32 + (cl ^ ((rowa >> 1) & 3)) * 8;
    int rowb = wn * 64 + r * 16 + (lane & 15);
    boff[r] = rowb * 32 + (cl ^ ((rowb >> 1) & 3)) * 8;
  }
  // staging coords: 512 16B-chunks per tile, 2 per thread; physical chunk
  // (row,cp) holds global chunk cg = cp ^ ((row>>1)&3)
  int srow[2], scg[2];
#pragma unroll
  for (int it = 0; it < 2; ++it) {
    int ch = wave * 64 + it * 256 + lane;
    srow[it] = ch >> 2;
    scg[it]  = (ch & 3) ^ ((srow[it] >> 1) & 3);
  }

#define STAGE(bf_, k0_)                                                        \
  do {                                                                         \
    _Pragma("unroll")                                                          \
    for (int it = 0; it < 2; ++it) {                                           \
      gld_lds16(A + (size_t)(m0 + srow[it]) * (size_t)lda +                    \
                    ((k0_) + scg[it] * 8),                                     \
                &ldsA[bf_][(wave * 64 + it * 256) * 8]);                       \
      gld_lds16(B + (size_t)(n0 + srow[it]) * (size_t)ldb +                    \
                    ((k0_) + scg[it] * 8),                                     \
                &ldsB[bf_][(wave * 64 + it * 256) * 8]);                       \
    }                                                                          \
  } while (0)

  const int Kc   = K / ksplit;
  const int kbeg = ks * Kc;
  const int nt   = Kc / 32;

  STAGE(0, kbeg);
  for (int t = 0; t < nt; ++t) {
    const int cur = t & 1;
    if (t + 1 < nt) {
      STAGE(cur ^ 1, kbeg + (t + 1) * 32);
      asm volatile("s_waitcnt vmcnt(4)" ::: "memory");  // tile t landed
    } else {
      asm volatile("s_waitcnt vmcnt(0)" ::: "memory");
    }
    __builtin_amdgcn_s_barrier();
    __builtin_amdgcn_sched_barrier(0);
    f16x8 af[4], bf[4];
#pragma unroll
    for (int r = 0; r < 4; ++r) af[r] = *(const f16x8*)&ldsA[cur][aoff[r]];
#pragma unroll
    for (int r = 0; r < 4; ++r) bf[r] = *(const f16x8*)&ldsB[cur][boff[r]];
#pragma unroll
    for (int mr = 0; mr < 4; ++mr)
#pragma unroll
      for (int nr = 0; nr < 4; ++nr)
        acc[mr][nr] = __builtin_amdgcn_mfma_f32_16x16x32_f16(
            af[mr], bf[nr], acc[mr][nr], 0, 0, 0);
    __builtin_amdgcn_sched_barrier(0);
    __builtin_amdgcn_s_barrier();   // readers done before next STAGE overwrite
    __builtin_amdgcn_sched_barrier(0);
  }
#undef STAGE

  const size_t cz = (ksplit > 1) ? (size_t)blockIdx.z : (size_t)zb;
  float* c32 = C32 ? C32 + cz * (size_t)sCb : nullptr;
  f16*   c16 = C16 ? C16 + cz * (size_t)sCb : nullptr;
  // C/D layout [m89]: col = lane&15, row = (lane>>4)*4 + reg
#pragma unroll
  for (int mr = 0; mr < 4; ++mr) {
#pragma unroll
    for (int r = 0; r < 4; ++r) {
      int grow = m0 + wm * 64 + mr * 16 + (lane >> 4) * 4 + r;
      float brv = bias_row ? bias_row[grow] : 0.f;
      float cav = crossA ? crossA[grow] : 0.f;
#pragma unroll
      for (int nr = 0; nr < 4; ++nr) {
        int gcol = n0 + wn * 64 + nr * 16 + (lane & 15);
        float v = acc[mr][nr][r] * scale + brv +
                  (bias_col ? bias_col[gcol] : 0.f) +
                  (crossB ? cav * crossB[gcol] : 0.f);
        if (c32) c32[(size_t)grow * N + gcol] = v;
        else     c16[(size_t)grow * N + gcol] = (f16)v;
      }
    }
  }
}

// ---------------- reduce 4 split-K partial slices -------------------------
// Partials p laid out as [batch][4][2^19] f32. Output flat [batch][2^19],
// f32 (o32) or f16 (o16). n4 = total output elems / 4.
__global__ __launch_bounds__(256) void reduce_ks4(
    const float4* __restrict__ p, float4* __restrict__ o32,
    f16* __restrict__ o16, unsigned n4)
{
  const unsigned pb4 = (1u << 19) / 4;  // per-batch float4 count
  unsigned i = blockIdx.x * 256u + threadIdx.x;
  const unsigned stride = gridDim.x * 256u;
  for (; i < n4; i += stride) {
    unsigned g = i / pb4, r = i - g * pb4;
    size_t base = ((size_t)g * 4u) * pb4 + r;
    float4 a = p[base];
    float4 b = p[base + pb4];
    float4 c = p[base + 2u * pb4];
    float4 d = p[base + 3u * pb4];
    float4 s = {a.x + b.x + c.x + d.x, a.y + b.y + c.y + d.y,
                a.z + b.z + c.z + d.z, a.w + b.w + c.w + d.w};
    if (o32) o32[i] = s;
    else {
      f16x4 h; h[0] = (f16)s.x; h[1] = (f16)s.y;
      h[2] = (f16)s.z; h[3] = (f16)s.w;
      *(f16x4*)(o16 + (size_t)i * 4) = h;
    }
  }
}

// ---------------- f32 -> f16 ----------------
__global__ __launch_bounds__(256) void cvt_f32_to_f16(
    const float* __restrict__ in, f16* __restrict__ out, unsigned n)
{
  unsigned i = (blockIdx.x * 256u + threadIdx.x) * 4u;
  if (i >= n) return;
  const float4 v = *(const float4*)(in + i);
  f16x4 h;
  h[0] = (f16)v.x; h[1] = (f16)v.y; h[2] = (f16)v.z; h[3] = (f16)v.w;
  *(f16x4*)(out + i) = h;
}

// ---------------- text (B,S,D) f32 -> textT (B,D,S) f16 ------------------
// 64(s) x 32(d) tiles; reads 128B rows, writes 128B rows, padded LDS.
__global__ __launch_bounds__(256) void transpose_text(
    const float* __restrict__ in, f16* __restrict__ out)
{
  __shared__ float t[32][65];
  const int b = blockIdx.z;
  const int s0 = blockIdx.x * 64, d0 = blockIdx.y * 32;
  const int dx = threadIdx.x & 31;
  const int sy = threadIdx.x >> 5;       // 0..7
  const float* ip = in + ((size_t)b * S_ + s0) * D_ + d0;
#pragma unroll
  for (int j = 0; j < 8; ++j) {
    int sl = j * 8 + sy;
    t[dx][sl] = ip[(size_t)sl * D_ + dx];
  }
  __syncthreads();
  const int sx = threadIdx.x & 63;
  const int dy = threadIdx.x >> 6;       // 0..3
  f16* op = out + ((size_t)b * D_ + d0) * S_ + s0;
#pragma unroll
  for (int j = 0; j < 8; ++j) {
    int dl = j * 4 + dy;
    op[(size_t)dl * S_ + sx] = (f16)t[dl][sx];
  }
}

// ---------------- row sums of Wb2s (S, IB): A[s] = sum_j W[s,j] ----------
__global__ __launch_bounds__(256) void rowsum_kernel(
    const float* __restrict__ W, float* __restrict__ out)
{
  int s = blockIdx.x;
  const float* row = W + (size_t)s * IB_;
  float acc = 0.f;
  for (int j = threadIdx.x; j < IB_; j += 256) acc += row[j];
  __shared__ float red[4];
#pragma unroll
  for (int o = 32; o >= 1; o >>= 1) acc += __shfl_xor(acc, o);
  if ((threadIdx.x & 63) == 0) red[threadIdx.x >> 6] = acc;
  __syncthreads();
  if (threadIdx.x == 0) out[s] = red[0] + red[1] + red[2] + red[3];
}

// ---------------- transpose Wb2s (S, IB) -> WT (IB, S), f32 --------------
__global__ __launch_bounds__(256) void transpose_f32(
    const float* __restrict__ in, float* __restrict__ out)
{
  __shared__ float t[32][33];
  int c0 = blockIdx.x * 32;          // col in 'in' (j)
  int r0 = blockIdx.y * 32;          // row in 'in' (s)
  int tx = threadIdx.x & 31, ty = threadIdx.x >> 5;
  for (int j = ty; j < 32; j += 8)
    t[j][tx] = in[(size_t)(r0 + j) * IB_ + c0 + tx];
  __syncthreads();
  for (int j = ty; j < 32; j += 8)
    out[(size_t)(c0 + j) * S_ + r0 + tx] = t[tx][j];
}

// ---------------- banded-softmax row + top-k(2050) -> sparse f16 + rowsum -
__device__ __forceinline__ unsigned fkey(float x) {
  unsigned u = __float_as_uint(x);
  return (u & 0x80000000u) ? ~u : (u | 0x80000000u);
}

__global__ __launch_bounds__(256) void sparse_topk(
    const float* __restrict__ WT, const float* __restrict__ Acs,
    const float* __restrict__ bb2s, f16* __restrict__ sp,
    float* __restrict__ rsum)
{
  const int i = blockIdx.x;   // 0..IB-1
  __shared__ float vals[S_];
  __shared__ unsigned hist[256];
  __shared__ unsigned sprefix;
  __shared__ int srem;
  __shared__ float rred[4];
  const float e1 = 2.71828182845904523536f;
  const int n1 = (i == 0 || i == IB_ - 1) ? 2 : 3;
  const float Z = (float)n1 * e1 + (float)(IB_ - n1);
  const float alpha = 1.f / Z;
  const float beta  = (e1 - 1.f) / Z;
  const float* wmid = WT + (size_t)i * S_;
  const float* wlo  = (i > 0)       ? WT + (size_t)(i - 1) * S_ : nullptr;
  const float* whi  = (i < IB_ - 1) ? WT + (size_t)(i + 1) * S_ : nullptr;
  for (int s = threadIdx.x; s < S_; s += 256) {
    float band = wmid[s];
    if (wlo) band += wlo[s];
    if (whi) band += whi[s];
    vals[s] = alpha * Acs[s] + beta * band + bb2s[s];
  }
  if (threadIdx.x == 0) { sprefix = 0u; srem = S_ / 2 + 2; }  // 2050
  __syncthreads();
  for (int shift = 24; shift >= 0; shift -= 8) {
    hist[threadIdx.x] = 0u;
    __syncthreads();
    unsigned pfx = sprefix;
    unsigned himask = (shift == 24) ? 0u : (0xFFFFFFFFu << (shift + 8));
    for (int s = threadIdx.x; s < S_; s += 256) {
      unsigned key = fkey(vals[s]);
      if ((key & himask) == (pfx & himask))
        atomicAdd(&hist[(key >> shift) & 255u], 1u);
    }
    __syncthreads();
    if (threadIdx.x == 0) {
      int rem = srem;
      unsigned acc = 0;
      int b = 255;
      for (; b > 0; --b) {
        unsigned c = hist[b];
        if (acc + c >= (unsigned)rem) break;
        acc += c;
      }
      sprefix = pfx | ((unsigned)b << shift);
      srem = rem - (int)acc;
    }
    __syncthreads();
  }
  const unsigned T = sprefix;
  float myrs = 0.f;
  for (int s = threadIdx.x; s < S_; s += 256) {
    float v = vals[s];
    bool keep = fkey(v) >= T;
    sp[(size_t)i * S_ + s] = keep ? (f16)v : (f16)0.f;
    if (keep) myrs += v;
  }
#pragma unroll
  for (int o = 32; o >= 1; o >>= 1) myrs += __shfl_xor(myrs, o);
  if ((threadIdx.x & 63) == 0) rred[threadIdx.x >> 6] = myrs;
  __syncthreads();
  if (threadIdx.x == 0) rsum[i] = rred[0] + rred[1] + rred[2] + rred[3];
}

// ---------------- in-place row softmax over f16 rows of length S ---------
__global__ __launch_bounds__(256) void softmax_rows_f16(f16* __restrict__ L)
{
  f16* row = L + (size_t)blockIdx.x * S_;
  const int t = threadIdx.x;
  __shared__ float red[4];
  f16x8 a = *(const f16x8*)(row + t * 8);
  f16x8 b = *(const f16x8*)(row + 2048 + t * 8);
  float v[16];
#pragma unroll
  for (int j = 0; j < 8; ++j) { v[j] = (float)a[j]; v[8 + j] = (float)b[j]; }
  float mx = -3.4e38f;
#pragma unroll
  for (int j = 0; j < 16; ++j) mx = fmaxf(mx, v[j]);
#pragma unroll
  for (int o = 32; o >= 1; o >>= 1) mx = fmaxf(mx, __shfl_xor(mx, o));
  if ((t & 63) == 0) red[t >> 6] = mx;
  __syncthreads();
  mx = fmaxf(fmaxf(red[0], red[1]), fmaxf(red[2], red[3]));
  __syncthreads();
  float sum = 0.f;
#pragma unroll
  for (int j = 0; j < 16; ++j) { v[j] = __expf(v[j] - mx); sum += v[j]; }
#pragma unroll
  for (int o = 32; o >= 1; o >>= 1) sum += __shfl_xor(sum, o);
  if ((t & 63) == 0) red[t >> 6] = sum;
  __syncthreads();
  sum = red[0] + red[1] + red[2] + red[3];
  const float inv = 1.f / sum;
#pragma unroll
  for (int j = 0; j < 8; ++j) {
    a[j] = (f16)(v[j] * inv); b[j] = (f16)(v[8 + j] * inv);
  }
  *(f16x8*)(row + t * 8) = a;
  *(f16x8*)(row + 2048 + t * 8) = b;
}

// =========================================================================
extern "C" void kernel_launch(void* const* d_in, const int* in_sizes, int n_in,
                              void* d_out, int out_size, void* d_ws, size_t ws_size,
                              hipStream_t stream)
{
  const float* text = (const float*)d_in[0];   // (B,S,D)
  const float* img  = (const float*)d_in[1];   // (B,IB,D)
  const float* Wq   = (const float*)d_in[2];
  const float* bq   = (const float*)d_in[3];
  const float* Wk   = (const float*)d_in[4];
  const float* bk   = (const float*)d_in[5];
  const float* Wv   = (const float*)d_in[6];
  const float* bv   = (const float*)d_in[7];
  const float* Wb2s = (const float*)d_in[8];   // (S,IB)
  const float* bb2s = (const float*)d_in[9];   // (S,)
  float* outp = (float*)d_out;
  char* ws = (char*)d_ws;

  const long long SD = (long long)S_ * D_;     // 2^21
  const long long DS = (long long)D_ * S_;
  const long long DI = (long long)D_ * IB_;    // 2^19
  const long long IS = (long long)IB_ * S_;    // 2^22
  const long long ID = (long long)IB_ * D_;    // 2^19
  const size_t MB = 1048576ull;

  // ws layout (<= 200 MiB, proved available in round 2):
  //  [  0, 64)  WTf[2-3) 0-16 | Acs@16 | img16[2-4) 17-25 | wq16@25 |
  //             -> parts [5,10) | wk16@0 [5c-6) | wv16@0 [10c-11)
  //  [ 64, 96)  textT  [1 -> 10)
  //  [ 96,128)  rs@96 (4KB) [3->6) -> Nb [7->8)
  //  [128,136)  qb [4->8) -> pt16 [10b->11)
  //  [136,144)  ts16 [5b->6)   } overwritten by logits [8->10)
  //  [144,152)  MT16 [6->7)    }
  //  [136,200)  logits f16 [8->10)
  // d_out: sparse [3->5) 0-8 | W16 [2->7) 8-16; final GEMM writes d_out at 11.
  const size_t NEED = 200 * MB;
  if (ws_size < NEED) return;

  float* WTf    = (float*)(ws + 0);
  float* Acs    = (float*)(ws + 16 * MB);
  f16*   img16  = (f16*)(ws + 17 * MB);
  f16*   wq16   = (f16*)(ws + 25 * MB);
  f16*   wk16   = (f16*)(ws + 0);
  f16*   wv16   = (f16*)(ws + 0);
  float* parts  = (float*)(ws + 0);
  f16*   textT  = (f16*)(ws + 64 * MB);
  float* rs     = (float*)(ws + 96 * MB);
  f16*   Nb     = (f16*)(ws + 96 * MB);
  f16*   qb     = (f16*)(ws + 128 * MB);
  f16*   pt16   = (f16*)(ws + 128 * MB);
  f16*   ts16   = (f16*)(ws + 136 * MB);
  f16*   MT16   = (f16*)(ws + 144 * MB);
  f16*   logits = (f16*)(ws + 136 * MB);
  f16*   sparse = (f16*)d_out;
  f16*   W16    = (f16*)((char*)d_out + 8 * MB);

  dim3 blk(256);
  const float scl = 0.04419417382415922f;  // 1/sqrt(512)
  const int KS = 4;

  // 1) text (B,S,D) f32 -> textT (B,D,S) f16
  transpose_text<<<dim3(S_/64, D_/32, B_), blk, 0, stream>>>(text, textT);
  // 2) conversions + sparse-pattern prep
  cvt_f32_to_f16<<<(B_*IB_*D_)/1024, blk, 0, stream>>>(img, img16, B_*IB_*D_);
  cvt_f32_to_f16<<<(S_*IB_)/1024, blk, 0, stream>>>(Wb2s, W16, S_*IB_);
  cvt_f32_to_f16<<<(D_*D_)/1024, blk, 0, stream>>>(Wq, wq16, D_*D_);
  rowsum_kernel<<<S_, blk, 0, stream>>>(Wb2s, Acs);
  transpose_f32<<<dim3(IB_/32, S_/32), blk, 0, stream>>>(Wb2s, WTf);
  // 3) top-k -> sparse f16 + row-sums rs
  sparse_topk<<<IB_, blk, 0, stream>>>(WTf, Acs, bb2s, sparse, rs);
  // 4) q = img @ Wq^T + bq : (B*IB, D) f16
  gemm_bt<<<dim3(D_/128, (B_*IB_)/128, 1), blk, 0, stream>>>(
      img16, wq16, nullptr, qb, B_*IB_, D_, D_, D_, D_, 1,
      0, 0, 0, nullptr, bq, nullptr, nullptr, 1.f);
  // 5) ts_b = sparse @ text_b : (IB, D) x B, two-stage split-K=4
  gemm_bt<<<dim3(D_/128, IB_/128, B_*KS), blk, 0, stream>>>(
      sparse, textT, parts, nullptr, IB_, D_, S_, S_, S_, KS,
      0, DS, ID, nullptr, nullptr, nullptr, nullptr, 1.f);
  // 5b) reduce -> ts16 f16
  reduce_ks4<<<2048, blk, 0, stream>>>(
      (const float4*)parts, nullptr, ts16, (unsigned)((B_*ID) / 4));
  // 5c) Wk -> f16 (parts region now dead)
  cvt_f32_to_f16<<<(D_*D_)/1024, blk, 0, stream>>>(Wk, wk16, D_*D_);
  // 6) MT_b = Wk @ ts_b^T + bk (x) rs : (D, IB) x B   [= M_b^T]
  gemm_bt<<<dim3(IB_/128, D_/128, B_), blk, 0, stream>>>(
      wk16, ts16, nullptr, MT16, D_, IB_, D_, D_, D_, 1,
      0, ID, DI, nullptr, nullptr, bk, rs, 1.f);
  // 7) N_b = Wb2s @ MT_b^T : (S, D) x B
  gemm_bt<<<dim3(D_/128, S_/128, B_), blk, 0, stream>>>(
      W16, MT16, nullptr, Nb, S_, D_, IB_, IB_, IB_, 1,
      0, DI, SD, nullptr, nullptr, nullptr, nullptr, 1.f);
  // 8) logits_b = q_b @ N_b^T * scl + bb2s : (IB, S) f16 x B
  gemm_bt<<<dim3(S_/128, IB_/128, B_), blk, 0, stream>>>(
      qb, Nb, nullptr, logits, IB_, S_, D_, D_, D_, 1,
      ID, SD, IS, nullptr, bb2s, nullptr, nullptr, scl);
  // 9) row softmax, in place on f16 rows
  softmax_rows_f16<<<B_*IB_, blk, 0, stream>>>(logits);
  // 10) pt_b = P_b @ text_b : (IB, D) x B, two-stage split-K=4
  gemm_bt<<<dim3(D_/128, IB_/128, B_*KS), blk, 0, stream>>>(
      logits, textT, parts, nullptr, IB_, D_, S_, S_, S_, KS,
      IS, DS, ID, nullptr, nullptr, nullptr, nullptr, 1.f);
  // 10b) reduce -> pt16 f16
  reduce_ks4<<<2048, blk, 0, stream>>>(
      (const float4*)parts, nullptr, pt16, (unsigned)((B_*ID) / 4));
  // 10c) Wv -> f16 (parts region dead again)
  cvt_f32_to_f16<<<(D_*D_)/1024, blk, 0, stream>>>(Wv, wv16, D_*D_);
  // 11) out = pt @ Wv^T + bv : (B*IB, D) f32 -> d_out  (softmax rows sum
  //     to 1, so P @ bv-broadcast == bv exactly)
  gemm_bt<<<dim3(D_/128, (B_*IB_)/128, 1), blk, 0, stream>>>(
      pt16, wv16, outp, nullptr, B_*IB_, D_, D_, D_, D_, 1,
      0, 0, 0, nullptr, bv, nullptr, nullptr, 1.f);
}

// Round 6
// 364.555 us; speedup vs baseline: 1.8851x; 1.4540x over previous
//
#include <hip/hip_runtime.h>

#define B_  8
#define IB_ 1024
#define S_  4096
#define D_  512

typedef _Float16 f16;
typedef _Float16 f16x8 __attribute__((ext_vector_type(8)));
typedef _Float16 f16x4 __attribute__((ext_vector_type(4)));
typedef float    f32x4 __attribute__((ext_vector_type(4)));

// ---------------- async global->LDS, 16B per lane ----------------
__device__ __forceinline__ void gld_lds16(const f16* g, f16* l) {
  __builtin_amdgcn_global_load_lds(
      (const __attribute__((address_space(1))) void*)g,
      (__attribute__((address_space(3))) void*)l, 16, 0, 0);
}

// ---------------- generic C = A(M,K) * B(N,K)^T  (f16 in, f32 accum) -------
// PROVEN r2-r5. 128x128 tile, BK=32, 4 waves, 2-phase prefetch (dbuf LDS,
// counted vmcnt). ksplit>1: grid.z = batch*ksplit, slice stores partials to
// C32 + blockIdx.z*sCb (two-stage split-K; reduce_ks4 sums afterwards).
__global__ __launch_bounds__(256) void gemm_bt(
    const f16* __restrict__ A, const f16* __restrict__ B,
    float* __restrict__ C32, f16* __restrict__ C16,
    int M, int N, int K, int lda, int ldb, int ksplit,
    long long sAb, long long sBb, long long sCb,
    const float* __restrict__ bias_row, const float* __restrict__ bias_col,
    float scale)
{
  __shared__ f16 ldsA[2][128 * 32];
  __shared__ f16 ldsB[2][128 * 32];
  const int tid  = threadIdx.x;
  const int lane = tid & 63;
  const int wave = tid >> 6;
  const int zb   = blockIdx.z / ksplit;
  const int ks   = blockIdx.z % ksplit;
  A += (size_t)zb * (size_t)sAb;
  B += (size_t)zb * (size_t)sBb;
  const int m0 = blockIdx.y * 128;
  const int n0 = blockIdx.x * 128;
  const int wm = wave >> 1, wn = wave & 1;

  f32x4 acc[4][4];
#pragma unroll
  for (int i = 0; i < 4; ++i)
#pragma unroll
    for (int j = 0; j < 4; ++j) acc[i][j] = (f32x4){0.f, 0.f, 0.f, 0.f};

  int aoff[4], boff[4];
  const int cl = lane >> 4;
#pragma unroll
  for (int r = 0; r < 4; ++r) {
    int rowa = wm * 64 + r * 16 + (lane & 15);
    aoff[r] = rowa * 32 + (cl ^ ((rowa >> 1) & 3)) * 8;
    int rowb = wn * 64 + r * 16 + (lane & 15);
    boff[r] = rowb * 32 + (cl ^ ((rowb >> 1) & 3)) * 8;
  }
  int srow[2], scg[2];
#pragma unroll
  for (int it = 0; it < 2; ++it) {
    int ch = wave * 64 + it * 256 + lane;
    srow[it] = ch >> 2;
    scg[it]  = (ch & 3) ^ ((srow[it] >> 1) & 3);
  }

#define STAGE(bf_, k0_)                                                        \
  do {                                                                         \
    _Pragma("unroll")                                                          \
    for (int it = 0; it < 2; ++it) {                                           \
      gld_lds16(A + (size_t)(m0 + srow[it]) * (size_t)lda +                    \
                    ((k0_) + scg[it] * 8),                                     \
                &ldsA[bf_][(wave * 64 + it * 256) * 8]);                       \
      gld_lds16(B + (size_t)(n0 + srow[it]) * (size_t)ldb +                    \
                    ((k0_) + scg[it] * 8),                                     \
                &ldsB[bf_][(wave * 64 + it * 256) * 8]);                       \
    }                                                                          \
  } while (0)

  const int Kc   = K / ksplit;
  const int kbeg = ks * Kc;
  const int nt   = Kc / 32;

  STAGE(0, kbeg);
  for (int t = 0; t < nt; ++t) {
    const int cur = t & 1;
    if (t + 1 < nt) {
      STAGE(cur ^ 1, kbeg + (t + 1) * 32);
      asm volatile("s_waitcnt vmcnt(4)" ::: "memory");
    } else {
      asm volatile("s_waitcnt vmcnt(0)" ::: "memory");
    }
    __builtin_amdgcn_s_barrier();
    __builtin_amdgcn_sched_barrier(0);
    f16x8 af[4], bf[4];
#pragma unroll
    for (int r = 0; r < 4; ++r) af[r] = *(const f16x8*)&ldsA[cur][aoff[r]];
#pragma unroll
    for (int r = 0; r < 4; ++r) bf[r] = *(const f16x8*)&ldsB[cur][boff[r]];
#pragma unroll
    for (int mr = 0; mr < 4; ++mr)
#pragma unroll
      for (int nr = 0; nr < 4; ++nr)
        acc[mr][nr] = __builtin_amdgcn_mfma_f32_16x16x32_f16(
            af[mr], bf[nr], acc[mr][nr], 0, 0, 0);
    __builtin_amdgcn_sched_barrier(0);
    __builtin_amdgcn_s_barrier();
    __builtin_amdgcn_sched_barrier(0);
  }
#undef STAGE

  const size_t cz = (ksplit > 1) ? (size_t)blockIdx.z : (size_t)zb;
  float* c32 = C32 ? C32 + cz * (size_t)sCb : nullptr;
  f16*   c16 = C16 ? C16 + cz * (size_t)sCb : nullptr;
#pragma unroll
  for (int mr = 0; mr < 4; ++mr) {
#pragma unroll
    for (int r = 0; r < 4; ++r) {
      int grow = m0 + wm * 64 + mr * 16 + (lane >> 4) * 4 + r;
      float brv = bias_row ? bias_row[grow] : 0.f;
#pragma unroll
      for (int nr = 0; nr < 4; ++nr) {
        int gcol = n0 + wn * 64 + nr * 16 + (lane & 15);
        float v = acc[mr][nr][r] * scale + brv +
                  (bias_col ? bias_col[gcol] : 0.f);
        if (c32) c32[(size_t)grow * N + gcol] = v;
        else     c16[(size_t)grow * N + gcol] = (f16)v;
      }
    }
  }
}

// ---------------- reduce 4 split-K partial slices -------------------------
__global__ __launch_bounds__(256) void reduce_ks4(
    const float4* __restrict__ p, float4* __restrict__ o32,
    f16* __restrict__ o16, unsigned n4)
{
  const unsigned pb4 = (1u << 19) / 4;
  unsigned i = blockIdx.x * 256u + threadIdx.x;
  const unsigned stride = gridDim.x * 256u;
  for (; i < n4; i += stride) {
    unsigned g = i / pb4, r = i - g * pb4;
    size_t base = ((size_t)g * 4u) * pb4 + r;
    float4 a = p[base];
    float4 b = p[base + pb4];
    float4 c = p[base + 2u * pb4];
    float4 d = p[base + 3u * pb4];
    float4 s = {a.x + b.x + c.x + d.x, a.y + b.y + c.y + d.y,
                a.z + b.z + c.z + d.z, a.w + b.w + c.w + d.w};
    if (o32) o32[i] = s;
    else {
      f16x4 h; h[0] = (f16)s.x; h[1] = (f16)s.y;
      h[2] = (f16)s.z; h[3] = (f16)s.w;
      *(f16x4*)(o16 + (size_t)i * 4) = h;
    }
  }
}

// ---------------- f32 -> f16 ----------------
__global__ __launch_bounds__(256) void cvt_f32_to_f16(
    const float* __restrict__ in, f16* __restrict__ out, unsigned n)
{
  unsigned i = (blockIdx.x * 256u + threadIdx.x) * 4u;
  if (i >= n) return;
  const float4 v = *(const float4*)(in + i);
  f16x4 h;
  h[0] = (f16)v.x; h[1] = (f16)v.y; h[2] = (f16)v.z; h[3] = (f16)v.w;
  *(f16x4*)(out + i) = h;
}

// ---------------- text (B,S,D) f32 -> textT (B,D,S) f16 ------------------
__global__ __launch_bounds__(256) void transpose_text(
    const float* __restrict__ in, f16* __restrict__ out)
{
  __shared__ float t[32][65];
  const int b = blockIdx.z;
  const int s0 = blockIdx.x * 64, d0 = blockIdx.y * 32;
  const int dx = threadIdx.x & 31;
  const int sy = threadIdx.x >> 5;
  const float* ip = in + ((size_t)b * S_ + s0) * D_ + d0;
#pragma unroll
  for (int j = 0; j < 8; ++j) {
    int sl = j * 8 + sy;
    t[dx][sl] = ip[(size_t)sl * D_ + dx];
  }
  __syncthreads();
  const int sx = threadIdx.x & 63;
  const int dy = threadIdx.x >> 6;
  f16* op = out + ((size_t)b * D_ + d0) * S_ + s0;
#pragma unroll
  for (int j = 0; j < 8; ++j) {
    int dl = j * 4 + dy;
    op[(size_t)dl * S_ + sx] = (f16)t[dl][sx];
  }
}

// ---------------- row sums of Wb2s (S, IB): Acs[s] = sum_j W[s,j] --------
__global__ __launch_bounds__(256) void rowsum_kernel(
    const float* __restrict__ W, float* __restrict__ out)
{
  int s = blockIdx.x;
  const float* row = W + (size_t)s * IB_;
  float acc = 0.f;
  for (int j = threadIdx.x; j < IB_; j += 256) acc += row[j];
  __shared__ float red[4];
#pragma unroll
  for (int o = 32; o >= 1; o >>= 1) acc += __shfl_xor(acc, o);
  if ((threadIdx.x & 63) == 0) red[threadIdx.x >> 6] = acc;
  __syncthreads();
  if (threadIdx.x == 0) out[s] = red[0] + red[1] + red[2] + red[3];
}

// ---------------- mu = alpha*Acs + bb2s, top-2050 mask, r̂ -----------------
__device__ __forceinline__ unsigned fkey(float x) {
  unsigned u = __float_as_uint(x);
  return (u & 0x80000000u) ? ~u : (u | 0x80000000u);
}

__global__ __launch_bounds__(256) void prep_mu(
    const float* __restrict__ Acs, const float* __restrict__ bb2s,
    float* __restrict__ muk, float* __restrict__ rhat)
{
  __shared__ float vals[S_];
  __shared__ unsigned hist[256];
  __shared__ unsigned sprefix;
  __shared__ int srem;
  __shared__ float rred[4];
  const float e1 = 2.71828182845904523536f;
  const float Z = 3.f * e1 + (float)(IB_ - 3);   // interior-row normalizer
  const float alpha = 1.f / Z;
  for (int s = threadIdx.x; s < S_; s += 256)
    vals[s] = alpha * Acs[s] + bb2s[s];
  if (threadIdx.x == 0) { sprefix = 0u; srem = S_ / 2 + 2; }  // 2050
  __syncthreads();
  for (int shift = 24; shift >= 0; shift -= 8) {
    hist[threadIdx.x] = 0u;
    __syncthreads();
    unsigned pfx = sprefix;
    unsigned himask = (shift == 24) ? 0u : (0xFFFFFFFFu << (shift + 8));
    for (int s = threadIdx.x; s < S_; s += 256) {
      unsigned key = fkey(vals[s]);
      if ((key & himask) == (pfx & himask))
        atomicAdd(&hist[(key >> shift) & 255u], 1u);
    }
    __syncthreads();
    if (threadIdx.x == 0) {
      int rem = srem;
      unsigned acc = 0;
      int b = 255;
      for (; b > 0; --b) {
        unsigned c = hist[b];
        if (acc + c >= (unsigned)rem) break;
        acc += c;
      }
      sprefix = pfx | ((unsigned)b << shift);
      srem = rem - (int)acc;
    }
    __syncthreads();
  }
  const unsigned T = sprefix;
  float myrs = 0.f;
  for (int s = threadIdx.x; s < S_; s += 256) {
    float v = vals[s];
    bool keep = fkey(v) >= T;
    muk[s] = keep ? v : 0.f;
    if (keep) myrs += v;
  }
#pragma unroll
  for (int o = 32; o >= 1; o >>= 1) myrs += __shfl_xor(myrs, o);
  if ((threadIdx.x & 63) == 0) rred[threadIdx.x >> 6] = myrs;
  __syncthreads();
  if (threadIdx.x == 0) rhat[0] = rred[0] + rred[1] + rred[2] + rred[3];
}

// ---------------- t̂ partials: tp[b][c][d] = sum_{s in chunk c} muk[s]*text -
__global__ __launch_bounds__(256) void that_partial(
    const float* __restrict__ text, const float* __restrict__ muk,
    float* __restrict__ tp)
{
  const int d = blockIdx.x * 256 + threadIdx.x;   // gridDim.x = 2
  const int c = blockIdx.y;                        // 32 chunks of 128 rows
  const int b = blockIdx.z;
  const float* tb = text + ((size_t)b * S_ + (size_t)c * 128) * D_ + d;
  float acc = 0.f;
  for (int s = 0; s < 128; ++s) {
    float m = muk[c * 128 + s];        // wave-uniform -> skips whole row load
    if (m != 0.f) acc += m * tb[(size_t)s * D_];
  }
  tp[((size_t)b * 32 + c) * D_ + d] = acc;
}

// ---------------- m̂[b] = Wk @ t̂_b + bk * r̂ -------------------------------
__global__ __launch_bounds__(256) void mhat_kernel(
    const float* __restrict__ tp, const float* __restrict__ Wk,
    const float* __restrict__ bk, const float* __restrict__ rhat,
    float* __restrict__ mh)
{
  __shared__ float tt[D_];
  const int b = blockIdx.x;
  for (int d = threadIdx.x; d < D_; d += 256) {
    float a = 0.f;
#pragma unroll
    for (int c = 0; c < 32; ++c) a += tp[((size_t)b * 32 + c) * D_ + d];
    tt[d] = a;
  }
  __syncthreads();
  const float rh = rhat[0];
  const int lane = threadIdx.x & 63, wave = threadIdx.x >> 6;
  for (int r = wave; r < D_; r += 4) {
    const float* wr = Wk + (size_t)r * D_;
    float acc = 0.f;
#pragma unroll
    for (int j = 0; j < 8; ++j) { int k = lane + 64 * j; acc += wr[k] * tt[k]; }
#pragma unroll
    for (int o = 32; o >= 1; o >>= 1) acc += __shfl_xor(acc, o);
    if (lane == 0) mh[b * D_ + r] = acc + bk[r] * rh;
  }
}

// ---------------- fused u + rank-1 logits + softmax -> P f16 --------------
// logits[i,s] = (q_i . m̂_b)*scl*Acs[s] + bb2s[s];  P = softmax_s(logits)
__global__ __launch_bounds__(256) void p_kernel(
    const f16* __restrict__ qb, const float* __restrict__ mh,
    const float* __restrict__ Acs, const float* __restrict__ bb2s,
    float scl, f16* __restrict__ P)
{
  const int row = blockIdx.x;            // b*IB + i
  const int b = row >> 10;
  const int t = threadIdx.x;
  __shared__ float red[4];
  const f16* qrow = qb + (size_t)row * D_;
  const float* mhb = mh + b * D_;
  float u = 0.f;
#pragma unroll
  for (int j = 0; j < 2; ++j) {
    int d = t + 256 * j;
    u += (float)qrow[d] * mhb[d];
  }
#pragma unroll
  for (int o = 32; o >= 1; o >>= 1) u += __shfl_xor(u, o);
  if ((t & 63) == 0) red[t >> 6] = u;
  __syncthreads();
  u = (red[0] + red[1] + red[2] + red[3]) * scl;
  __syncthreads();
  float v[16];
  float mx = -3.4e38f;
#pragma unroll
  for (int j = 0; j < 16; ++j) {
    int s = t + 256 * j;
    v[j] = u * Acs[s] + bb2s[s];
    mx = fmaxf(mx, v[j]);
  }
#pragma unroll
  for (int o = 32; o >= 1; o >>= 1) mx = fmaxf(mx, __shfl_xor(mx, o));
  if ((t & 63) == 0) red[t >> 6] = mx;
  __syncthreads();
  mx = fmaxf(fmaxf(red[0], red[1]), fmaxf(red[2], red[3]));
  __syncthreads();
  float sum = 0.f;
#pragma unroll
  for (int j = 0; j < 16; ++j) { v[j] = __expf(v[j] - mx); sum += v[j]; }
#pragma unroll
  for (int o = 32; o >= 1; o >>= 1) sum += __shfl_xor(sum, o);
  if ((t & 63) == 0) red[t >> 6] = sum;
  __syncthreads();
  sum = red[0] + red[1] + red[2] + red[3];
  const float inv = 1.f / sum;
  f16* prow = P + (size_t)row * S_;
#pragma unroll
  for (int j = 0; j < 16; ++j)
    prow[t + 256 * j] = (f16)(v[j] * inv);
}

// =========================================================================
extern "C" void kernel_launch(void* const* d_in, const int* in_sizes, int n_in,
                              void* d_out, int out_size, void* d_ws, size_t ws_size,
                              hipStream_t stream)
{
  const float* text = (const float*)d_in[0];   // (B,S,D)
  const float* img  = (const float*)d_in[1];   // (B,IB,D)
  const float* Wq   = (const float*)d_in[2];
  const float* bq   = (const float*)d_in[3];
  const float* Wk   = (const float*)d_in[4];
  const float* bk   = (const float*)d_in[5];
  const float* Wv   = (const float*)d_in[6];
  const float* bv   = (const float*)d_in[7];
  const float* Wb2s = (const float*)d_in[8];   // (S,IB)
  const float* bb2s = (const float*)d_in[9];   // (S,)
  float* outp = (float*)d_out;
  char* ws = (char*)d_ws;

  const long long SD = (long long)S_ * D_;
  const long long DS = (long long)D_ * S_;
  const long long IS = (long long)IB_ * S_;
  const long long ID = (long long)IB_ * D_;
  const size_t MB = 1048576ull;

  // ws layout (NEED = 200 MiB, proved available in round 2):
  //  [  0, 64)  textT f16  [5 -> pt)
  //  [ 64,128)  P f16 [9 -> 10)  -> pt16 [11 -> 13) at 64..72
  //  [128,192)  img16 [6->8) 128-136 | wq16@136 [7->8) | smalls@140 [1->9)
  //             -> parts f32 [10 -> 11)  -> wv16@136 [12->13)
  //  [192,200)  qb f16 [8 -> 9)
  const size_t NEED = 200 * MB;
  if (ws_size < NEED) return;

  f16*   textT = (f16*)(ws + 0);
  f16*   P     = (f16*)(ws + 64 * MB);
  f16*   pt16  = (f16*)(ws + 64 * MB);
  float* parts = (float*)(ws + 128 * MB);
  f16*   img16 = (f16*)(ws + 128 * MB);
  f16*   wq16  = (f16*)(ws + 136 * MB);
  f16*   wv16  = (f16*)(ws + 136 * MB);
  float* Acs   = (float*)(ws + 140 * MB);
  float* muk   = (float*)(ws + 140 * MB + 16384);
  float* tp    = (float*)(ws + 140 * MB + 32768);      // 8*32*512 f32 = 512KB
  float* mh    = (float*)(ws + 140 * MB + 557056);
  float* rhat  = (float*)(ws + 140 * MB + 573440);
  f16*   qb    = (f16*)(ws + 192 * MB);

  dim3 blk(256);
  const float scl = 0.04419417382415922f;  // 1/sqrt(512)
  const int KS = 4;

  // 1) Acs = rowsum(Wb2s)
  rowsum_kernel<<<S_, blk, 0, stream>>>(Wb2s, Acs);
  // 2) mu + top-2050 mask + r̂
  prep_mu<<<1, blk, 0, stream>>>(Acs, bb2s, muk, rhat);
  // 3) t̂ partials (masked weighted row-sum of text, f32)
  that_partial<<<dim3(2, 32, B_), blk, 0, stream>>>(text, muk, tp);
  // 4) m̂_b = Wk @ t̂_b + bk*r̂
  mhat_kernel<<<B_, blk, 0, stream>>>(tp, Wk, bk, rhat, mh);
  // 5) textT (B,D,S) f16 — for the PV GEMM
  transpose_text<<<dim3(S_/64, D_/32, B_), blk, 0, stream>>>(text, textT);
  // 6) img -> f16
  cvt_f32_to_f16<<<(B_*IB_*D_)/1024, blk, 0, stream>>>(img, img16, B_*IB_*D_);
  // 7) Wq -> f16
  cvt_f32_to_f16<<<(D_*D_)/1024, blk, 0, stream>>>(Wq, wq16, D_*D_);
  // 8) q = img @ Wq^T + bq : (B*IB, D) f16
  gemm_bt<<<dim3(D_/128, (B_*IB_)/128, 1), blk, 0, stream>>>(
      img16, wq16, nullptr, qb, B_*IB_, D_, D_, D_, D_, 1,
      0, 0, 0, nullptr, bq, 1.f);
  // 9) P = softmax_s( (q.m̂)*scl*Acs[s] + bb2s[s] ) : (B*IB, S) f16
  p_kernel<<<B_*IB_, blk, 0, stream>>>(qb, mh, Acs, bb2s, scl, P);
  // 10) pt_b = P_b @ text_b : (IB, D) x B, two-stage split-K=4
  gemm_bt<<<dim3(D_/128, IB_/128, B_*KS), blk, 0, stream>>>(
      P, textT, parts, nullptr, IB_, D_, S_, S_, S_, KS,
      IS, DS, ID, nullptr, nullptr, 1.f);
  // 11) reduce partials -> pt16 f16
  reduce_ks4<<<2048, blk, 0, stream>>>(
      (const float4*)parts, nullptr, pt16, (unsigned)((B_*ID) / 4));
  // 12) Wv -> f16
  cvt_f32_to_f16<<<(D_*D_)/1024, blk, 0, stream>>>(Wv, wv16, D_*D_);
  // 13) out = pt @ Wv^T + bv : (B*IB, D) f32 -> d_out  (softmax rows sum
  //     to 1, so P @ bv-broadcast == bv exactly)
  gemm_bt<<<dim3(D_/128, (B_*IB_)/128, 1), blk, 0, stream>>>(
      pt16, wv16, outp, nullptr, B_*IB_, D_, D_, D_, D_, 1,
      0, 0, 0, nullptr, bv, 1.f);
}

// Round 7
// 249.654 us; speedup vs baseline: 2.7527x; 1.4602x over previous
//
#include <hip/hip_runtime.h>

#define B_  8
#define IB_ 1024
#define S_  4096
#define D_  512

typedef _Float16 f16;
typedef _Float16 f16x8 __attribute__((ext_vector_type(8)));
typedef _Float16 f16x4 __attribute__((ext_vector_type(4)));
typedef float    f32x4 __attribute__((ext_vector_type(4)));

// ---------------- async global->LDS, 16B per lane ----------------
__device__ __forceinline__ void gld_lds16(const f16* g, f16* l) {
  __builtin_amdgcn_global_load_lds(
      (const __attribute__((address_space(1))) void*)g,
      (__attribute__((address_space(3))) void*)l, 16, 0, 0);
}

// ---------------- generic C = A(M,K) * B(N,K)^T  (f16 in, f32 accum) -------
// PROVEN r2-r6. 128x128 tile, BK=32, 4 waves, 2-phase prefetch (dbuf LDS,
// counted vmcnt). ksplit>1: grid.z = batch*ksplit, slice stores partials
// (f32 via C32 or f16 via C16) to C + blockIdx.z*sCb; reducer sums slices.
__global__ __launch_bounds__(256) void gemm_bt(
    const f16* __restrict__ A, const f16* __restrict__ B,
    float* __restrict__ C32, f16* __restrict__ C16,
    int M, int N, int K, int lda, int ldb, int ksplit,
    long long sAb, long long sBb, long long sCb,
    const float* __restrict__ bias_row, const float* __restrict__ bias_col,
    float scale)
{
  __shared__ f16 ldsA[2][128 * 32];
  __shared__ f16 ldsB[2][128 * 32];
  const int tid  = threadIdx.x;
  const int lane = tid & 63;
  const int wave = tid >> 6;
  const int zb   = blockIdx.z / ksplit;
  const int ks   = blockIdx.z % ksplit;
  A += (size_t)zb * (size_t)sAb;
  B += (size_t)zb * (size_t)sBb;
  const int m0 = blockIdx.y * 128;
  const int n0 = blockIdx.x * 128;
  const int wm = wave >> 1, wn = wave & 1;

  f32x4 acc[4][4];
#pragma unroll
  for (int i = 0; i < 4; ++i)
#pragma unroll
    for (int j = 0; j < 4; ++j) acc[i][j] = (f32x4){0.f, 0.f, 0.f, 0.f};

  int aoff[4], boff[4];
  const int cl = lane >> 4;
#pragma unroll
  for (int r = 0; r < 4; ++r) {
    int rowa = wm * 64 + r * 16 + (lane & 15);
    aoff[r] = rowa * 32 + (cl ^ ((rowa >> 1) & 3)) * 8;
    int rowb = wn * 64 + r * 16 + (lane & 15);
    boff[r] = rowb * 32 + (cl ^ ((rowb >> 1) & 3)) * 8;
  }
  int srow[2], scg[2];
#pragma unroll
  for (int it = 0; it < 2; ++it) {
    int ch = wave * 64 + it * 256 + lane;
    srow[it] = ch >> 2;
    scg[it]  = (ch & 3) ^ ((srow[it] >> 1) & 3);
  }

#define STAGE(bf_, k0_)                                                        \
  do {                                                                         \
    _Pragma("unroll")                                                          \
    for (int it = 0; it < 2; ++it) {                                           \
      gld_lds16(A + (size_t)(m0 + srow[it]) * (size_t)lda +                    \
                    ((k0_) + scg[it] * 8),                                     \
                &ldsA[bf_][(wave * 64 + it * 256) * 8]);                       \
      gld_lds16(B + (size_t)(n0 + srow[it]) * (size_t)ldb +                    \
                    ((k0_) + scg[it] * 8),                                     \
                &ldsB[bf_][(wave * 64 + it * 256) * 8]);                       \
    }                                                                          \
  } while (0)

  const int Kc   = K / ksplit;
  const int kbeg = ks * Kc;
  const int nt   = Kc / 32;

  STAGE(0, kbeg);
  for (int t = 0; t < nt; ++t) {
    const int cur = t & 1;
    if (t + 1 < nt) {
      STAGE(cur ^ 1, kbeg + (t + 1) * 32);
      asm volatile("s_waitcnt vmcnt(4)" ::: "memory");
    } else {
      asm volatile("s_waitcnt vmcnt(0)" ::: "memory");
    }
    __builtin_amdgcn_s_barrier();
    __builtin_amdgcn_sched_barrier(0);
    f16x8 af[4], bf[4];
#pragma unroll
    for (int r = 0; r < 4; ++r) af[r] = *(const f16x8*)&ldsA[cur][aoff[r]];
#pragma unroll
    for (int r = 0; r < 4; ++r) bf[r] = *(const f16x8*)&ldsB[cur][boff[r]];
#pragma unroll
    for (int mr = 0; mr < 4; ++mr)
#pragma unroll
      for (int nr = 0; nr < 4; ++nr)
        acc[mr][nr] = __builtin_amdgcn_mfma_f32_16x16x32_f16(
            af[mr], bf[nr], acc[mr][nr], 0, 0, 0);
    __builtin_amdgcn_sched_barrier(0);
    __builtin_amdgcn_s_barrier();
    __builtin_amdgcn_sched_barrier(0);
  }
#undef STAGE

  const size_t cz = (ksplit > 1) ? (size_t)blockIdx.z : (size_t)zb;
  float* c32 = C32 ? C32 + cz * (size_t)sCb : nullptr;
  f16*   c16 = C16 ? C16 + cz * (size_t)sCb : nullptr;
#pragma unroll
  for (int mr = 0; mr < 4; ++mr) {
#pragma unroll
    for (int r = 0; r < 4; ++r) {
      int grow = m0 + wm * 64 + mr * 16 + (lane >> 4) * 4 + r;
      float brv = bias_row ? bias_row[grow] : 0.f;
#pragma unroll
      for (int nr = 0; nr < 4; ++nr) {
        int gcol = n0 + wn * 64 + nr * 16 + (lane & 15);
        float v = acc[mr][nr][r] * scale + brv +
                  (bias_col ? bias_col[gcol] : 0.f);
        if (c32) c32[(size_t)grow * N + gcol] = v;
        else     c16[(size_t)grow * N + gcol] = (f16)v;
      }
    }
  }
}

// ---------------- reduce 8 f16 split-K slices: [B][8][ID] -> [B][ID] ------
__global__ __launch_bounds__(256) void reduce_ks8_f16(
    const f16x8* __restrict__ p, f16x8* __restrict__ o, unsigned n8)
{
  const unsigned pb8 = (IB_ * D_) / 8;   // 65536 f16x8 units per slice
  unsigned i = blockIdx.x * 256u + threadIdx.x;
  const unsigned stride = gridDim.x * 256u;
  for (; i < n8; i += stride) {
    unsigned g = i / pb8, r = i - g * pb8;
    size_t base = ((size_t)g * 8u) * pb8 + r;
    float acc[8] = {0.f, 0.f, 0.f, 0.f, 0.f, 0.f, 0.f, 0.f};
#pragma unroll
    for (int ks = 0; ks < 8; ++ks) {
      f16x8 v = p[base + (size_t)ks * pb8];
#pragma unroll
      for (int j = 0; j < 8; ++j) acc[j] += (float)v[j];
    }
    f16x8 h;
#pragma unroll
    for (int j = 0; j < 8; ++j) h[j] = (f16)acc[j];
    o[i] = h;
  }
}

// ---------------- f32 -> f16 ----------------
__global__ __launch_bounds__(256) void cvt_f32_to_f16(
    const float* __restrict__ in, f16* __restrict__ out, unsigned n)
{
  unsigned i = (blockIdx.x * 256u + threadIdx.x) * 4u;
  if (i >= n) return;
  const float4 v = *(const float4*)(in + i);
  f16x4 h;
  h[0] = (f16)v.x; h[1] = (f16)v.y; h[2] = (f16)v.z; h[3] = (f16)v.w;
  *(f16x4*)(out + i) = h;
}

// ---------------- text (B,S,D) f32 -> textT (B,D,S) f16 ------------------
__global__ __launch_bounds__(256) void transpose_text(
    const float* __restrict__ in, f16* __restrict__ out)
{
  __shared__ float t[32][65];
  const int b = blockIdx.z;
  const int s0 = blockIdx.x * 64, d0 = blockIdx.y * 32;
  const int dx = threadIdx.x & 31;
  const int sy = threadIdx.x >> 5;
  const float* ip = in + ((size_t)b * S_ + s0) * D_ + d0;
#pragma unroll
  for (int j = 0; j < 8; ++j) {
    int sl = j * 8 + sy;
    t[dx][sl] = ip[(size_t)sl * D_ + dx];
  }
  __syncthreads();
  const int sx = threadIdx.x & 63;
  const int dy = threadIdx.x >> 6;
  f16* op = out + ((size_t)b * D_ + d0) * S_ + s0;
#pragma unroll
  for (int j = 0; j < 8; ++j) {
    int dl = j * 4 + dy;
    op[(size_t)dl * S_ + sx] = (f16)t[dl][sx];
  }
}

// ---------------- row sums of Wb2s (S, IB): Acs[s] = sum_j W[s,j] --------
__global__ __launch_bounds__(256) void rowsum_kernel(
    const float* __restrict__ W, float* __restrict__ out)
{
  int s = blockIdx.x;
  const float* row = W + (size_t)s * IB_;
  float acc = 0.f;
  for (int j = threadIdx.x; j < IB_; j += 256) acc += row[j];
  __shared__ float red[4];
#pragma unroll
  for (int o = 32; o >= 1; o >>= 1) acc += __shfl_xor(acc, o);
  if ((threadIdx.x & 63) == 0) red[threadIdx.x >> 6] = acc;
  __syncthreads();
  if (threadIdx.x == 0) out[s] = red[0] + red[1] + red[2] + red[3];
}

// ---------------- mu = alpha*Acs + bb2s, top-2050 mask, r̂ -----------------
__device__ __forceinline__ unsigned fkey(float x) {
  unsigned u = __float_as_uint(x);
  return (u & 0x80000000u) ? ~u : (u | 0x80000000u);
}

__global__ __launch_bounds__(256) void prep_mu(
    const float* __restrict__ Acs, const float* __restrict__ bb2s,
    float* __restrict__ muk, float* __restrict__ rhat)
{
  __shared__ float vals[S_];
  __shared__ unsigned hist[256];
  __shared__ unsigned sprefix;
  __shared__ int srem;
  __shared__ float rred[4];
  const float e1 = 2.71828182845904523536f;
  const float Z = 3.f * e1 + (float)(IB_ - 3);   // interior-row normalizer
  const float alpha = 1.f / Z;
  for (int s = threadIdx.x; s < S_; s += 256)
    vals[s] = alpha * Acs[s] + bb2s[s];
  if (threadIdx.x == 0) { sprefix = 0u; srem = S_ / 2 + 2; }  // 2050
  __syncthreads();
  for (int shift = 24; shift >= 0; shift -= 8) {
    hist[threadIdx.x] = 0u;
    __syncthreads();
    unsigned pfx = sprefix;
    unsigned himask = (shift == 24) ? 0u : (0xFFFFFFFFu << (shift + 8));
    for (int s = threadIdx.x; s < S_; s += 256) {
      unsigned key = fkey(vals[s]);
      if ((key & himask) == (pfx & himask))
        atomicAdd(&hist[(key >> shift) & 255u], 1u);
    }
    __syncthreads();
    if (threadIdx.x == 0) {
      int rem = srem;
      unsigned acc = 0;
      int b = 255;
      for (; b > 0; --b) {
        unsigned c = hist[b];
        if (acc + c >= (unsigned)rem) break;
        acc += c;
      }
      sprefix = pfx | ((unsigned)b << shift);
      srem = rem - (int)acc;
    }
    __syncthreads();
  }
  const unsigned T = sprefix;
  float myrs = 0.f;
  for (int s = threadIdx.x; s < S_; s += 256) {
    float v = vals[s];
    bool keep = fkey(v) >= T;
    muk[s] = keep ? v : 0.f;
    if (keep) myrs += v;
  }
#pragma unroll
  for (int o = 32; o >= 1; o >>= 1) myrs += __shfl_xor(myrs, o);
  if ((threadIdx.x & 63) == 0) rred[threadIdx.x >> 6] = myrs;
  __syncthreads();
  if (threadIdx.x == 0) rhat[0] = rred[0] + rred[1] + rred[2] + rred[3];
}

// ---------------- t̂ partials: tp[b][c][d] = sum_{s in chunk c} muk[s]*text -
__global__ __launch_bounds__(256) void that_partial(
    const float* __restrict__ text, const float* __restrict__ muk,
    float* __restrict__ tp)
{
  const int d = blockIdx.x * 256 + threadIdx.x;   // gridDim.x = 2
  const int c = blockIdx.y;                        // 32 chunks of 128 rows
  const int b = blockIdx.z;
  const float* tb = text + ((size_t)b * S_ + (size_t)c * 128) * D_ + d;
  float acc = 0.f;
  for (int s = 0; s < 128; ++s) {
    float m = muk[c * 128 + s];        // wave-uniform -> skips whole row load
    if (m != 0.f) acc += m * tb[(size_t)s * D_];
  }
  tp[((size_t)b * 32 + c) * D_ + d] = acc;
}

// ---------------- tt[b][d] = sum_c tp[b][c][d] ---------------------------
__global__ __launch_bounds__(256) void tt_reduce(
    const float* __restrict__ tp, float* __restrict__ tt)
{
  const int d = blockIdx.x * 256 + threadIdx.x;   // gridDim.x = 2
  const int b = blockIdx.y;                        // gridDim.y = 8
  float acc = 0.f;
#pragma unroll
  for (int c = 0; c < 32; ++c) acc += tp[((size_t)b * 32 + c) * D_ + d];
  tt[(size_t)b * D_ + d] = acc;
}

// ---------------- m̂[b][r] = Wk[r,:].tt[b] + bk[r]*r̂ ; grid = 512 rows ----
__global__ __launch_bounds__(256) void mhat2_kernel(
    const float* __restrict__ tt, const float* __restrict__ Wk,
    const float* __restrict__ bk, const float* __restrict__ rhat,
    float* __restrict__ mh)
{
  __shared__ float tl[B_ * D_];        // 16 KB: all batches' t̂
  const int t = threadIdx.x;
  for (int i = t; i < B_ * D_; i += 256) tl[i] = tt[i];
  __syncthreads();
  const int r = blockIdx.x;
  const int lane = t & 63, wave = t >> 6;
  const float* wr = Wk + (size_t)r * D_;
  float w[8];
#pragma unroll
  for (int j = 0; j < 8; ++j) w[j] = wr[lane + 64 * j];
  const float bkr = bk[r] * rhat[0];
#pragma unroll
  for (int bb = 0; bb < 2; ++bb) {
    const int b = wave * 2 + bb;
    float acc = 0.f;
#pragma unroll
    for (int j = 0; j < 8; ++j) acc += w[j] * tl[b * D_ + lane + 64 * j];
#pragma unroll
    for (int o = 32; o >= 1; o >>= 1) acc += __shfl_xor(acc, o);
    if (lane == 0) mh[b * D_ + r] = acc + bkr;
  }
}

// ---------------- ypart[c][b][d] = sum_{r in chunk c} Wq[r,d]*mh[b][r] ----
__global__ __launch_bounds__(256) void ypart_kernel(
    const float* __restrict__ Wq, const float* __restrict__ mh,
    float* __restrict__ yp)
{
  __shared__ float ms[B_ * 64];        // mh slice: 8 batches x 64 rows
  const int t = threadIdx.x;
  const int d = blockIdx.x * 256 + t;  // gridDim.x = 2
  const int c = blockIdx.y;            // gridDim.y = 8 chunks of 64 rows
  for (int i = t; i < B_ * 64; i += 256) {
    int b = i >> 6, rr = i & 63;
    ms[i] = mh[b * D_ + c * 64 + rr];
  }
  __syncthreads();
  float acc[8] = {0.f, 0.f, 0.f, 0.f, 0.f, 0.f, 0.f, 0.f};
  for (int rr = 0; rr < 64; ++rr) {
    float wv = Wq[(size_t)(c * 64 + rr) * D_ + d];
#pragma unroll
    for (int b = 0; b < 8; ++b) acc[b] += wv * ms[b * 64 + rr];
  }
#pragma unroll
  for (int b = 0; b < 8; ++b)
    yp[((size_t)c * 8 + b) * D_ + d] = acc[b];
}

// ---------------- y[b][d] = sum_c ypart[c][b][d] -------------------------
__global__ __launch_bounds__(256) void yred_kernel(
    const float* __restrict__ yp, float* __restrict__ y)
{
  const int d = blockIdx.x * 256 + threadIdx.x;   // gridDim.x = 2
  const int b = blockIdx.y;                        // gridDim.y = 8
  float acc = 0.f;
#pragma unroll
  for (int c = 0; c < 8; ++c) acc += yp[((size_t)c * 8 + b) * D_ + d];
  y[(size_t)b * D_ + d] = acc;
}

// ---------------- cb[b] = bq . mh[b] -------------------------------------
__global__ __launch_bounds__(256) void cb_kernel(
    const float* __restrict__ bq, const float* __restrict__ mh,
    float* __restrict__ cb)
{
  const int lane = threadIdx.x & 63, wave = threadIdx.x >> 6;
#pragma unroll
  for (int bb = 0; bb < 2; ++bb) {
    const int b = wave * 2 + bb;
    float acc = 0.f;
#pragma unroll
    for (int j = 0; j < 8; ++j) {
      int k = lane + 64 * j;
      acc += bq[k] * mh[b * D_ + k];
    }
#pragma unroll
    for (int o = 32; o >= 1; o >>= 1) acc += __shfl_xor(acc, o);
    if (lane == 0) cb[b] = acc;
  }
}

// ---------------- u[row] = (img_row . y_b + cb[b]) * scl ------------------
__global__ __launch_bounds__(256) void u_kernel(
    const float* __restrict__ img, const float* __restrict__ y,
    const float* __restrict__ cb, float scl, float* __restrict__ u)
{
  const int lane = threadIdx.x & 63, wave = threadIdx.x >> 6;
  const int row = blockIdx.x * 4 + wave;          // grid = 2048
  const int b = row >> 10;
  const float* ir = img + (size_t)row * D_;
  const float* yb = y + (size_t)b * D_;
  float acc = 0.f;
#pragma unroll
  for (int j = 0; j < 8; ++j) {
    int d = lane + 64 * j;
    acc += ir[d] * yb[d];
  }
#pragma unroll
  for (int o = 32; o >= 1; o >>= 1) acc += __shfl_xor(acc, o);
  if (lane == 0) u[row] = (acc + cb[b]) * scl;
}

// ---------------- P[row][s] = softmax_s( u[row]*Acs[s] + bb2s[s] ), f16 ---
__global__ __launch_bounds__(256) void p_kernel(
    const float* __restrict__ uarr, const float* __restrict__ Acs,
    const float* __restrict__ bb2s, f16* __restrict__ P)
{
  const int row = blockIdx.x;            // b*IB + i
  const int t = threadIdx.x;
  __shared__ float red[4];
  const float u = uarr[row];
  float v[16];
  float mx = -3.4e38f;
#pragma unroll
  for (int j = 0; j < 16; ++j) {
    int s = t + 256 * j;
    v[j] = u * Acs[s] + bb2s[s];
    mx = fmaxf(mx, v[j]);
  }
#pragma unroll
  for (int o = 32; o >= 1; o >>= 1) mx = fmaxf(mx, __shfl_xor(mx, o));
  if ((t & 63) == 0) red[t >> 6] = mx;
  __syncthreads();
  mx = fmaxf(fmaxf(red[0], red[1]), fmaxf(red[2], red[3]));
  __syncthreads();
  float sum = 0.f;
#pragma unroll
  for (int j = 0; j < 16; ++j) { v[j] = __expf(v[j] - mx); sum += v[j]; }
#pragma unroll
  for (int o = 32; o >= 1; o >>= 1) sum += __shfl_xor(sum, o);
  if ((t & 63) == 0) red[t >> 6] = sum;
  __syncthreads();
  sum = red[0] + red[1] + red[2] + red[3];
  const float inv = 1.f / sum;
  f16* prow = P + (size_t)row * S_;
#pragma unroll
  for (int j = 0; j < 16; ++j)
    prow[t + 256 * j] = (f16)(v[j] * inv);
}

// =========================================================================
extern "C" void kernel_launch(void* const* d_in, const int* in_sizes, int n_in,
                              void* d_out, int out_size, void* d_ws, size_t ws_size,
                              hipStream_t stream)
{
  const float* text = (const float*)d_in[0];   // (B,S,D)
  const float* img  = (const float*)d_in[1];   // (B,IB,D)
  const float* Wq   = (const float*)d_in[2];
  const float* bq   = (const float*)d_in[3];
  const float* Wk   = (const float*)d_in[4];
  const float* bk   = (const float*)d_in[5];
  const float* Wv   = (const float*)d_in[6];
  const float* bv   = (const float*)d_in[7];
  const float* Wb2s = (const float*)d_in[8];   // (S,IB)
  const float* bb2s = (const float*)d_in[9];   // (S,)
  float* outp = (float*)d_out;
  char* ws = (char*)d_ws;

  const long long DS = (long long)D_ * S_;
  const long long IS = (long long)IB_ * S_;
  const long long ID = (long long)IB_ * D_;
  const size_t MB = 1048576ull;

  // ws layout (NEED = 200 MiB, proved available in round 2):
  //  [  0, 32)  textT f16 (B,D,S)
  //  [ 32, 96)  P f16 [p -> pt)   -> pt16 [reduce -> out) at 32..40
  //  [ 96,160)  parts16 f16, 64 slices x 1 MB  [pt -> reduce)
  //  [160,161)  wv16
  //  [161,...)  smalls: Acs, muk, tp, tt, mh, rhat, yp, y, cb, u
  const size_t NEED = 200 * MB;
  if (ws_size < NEED) return;

  f16*   textT   = (f16*)(ws + 0);
  f16*   P       = (f16*)(ws + 32 * MB);
  f16*   pt16    = (f16*)(ws + 32 * MB);
  f16*   parts16 = (f16*)(ws + 96 * MB);
  f16*   wv16    = (f16*)(ws + 160 * MB);
  const size_t SB = 161 * MB;
  float* Acs  = (float*)(ws + SB);
  float* muk  = (float*)(ws + SB + 16384);
  float* tp   = (float*)(ws + SB + 32768);        // 512 KB
  float* tt   = (float*)(ws + SB + 557056);
  float* mh   = (float*)(ws + SB + 573440);
  float* rhat = (float*)(ws + SB + 589824);
  float* yp   = (float*)(ws + SB + 593920);       // 128 KB
  float* y    = (float*)(ws + SB + 724992);
  float* cb   = (float*)(ws + SB + 741376);
  float* u    = (float*)(ws + SB + 745472);       // 32 KB

  dim3 blk(256);
  const float scl = 0.04419417382415922f;  // 1/sqrt(512)
  const int KS = 8;

  // 1) Acs = rowsum(Wb2s); mu + top-2050 mask + r̂
  rowsum_kernel<<<S_, blk, 0, stream>>>(Wb2s, Acs);
  prep_mu<<<1, blk, 0, stream>>>(Acs, bb2s, muk, rhat);
  // 2) t̂ = muk-weighted row-sum of text (partials + reduce)
  that_partial<<<dim3(2, 32, B_), blk, 0, stream>>>(text, muk, tp);
  tt_reduce<<<dim3(2, B_), blk, 0, stream>>>(tp, tt);
  // 3) m̂_b = Wk @ t̂_b + bk*r̂   (512 blocks — all CUs)
  mhat2_kernel<<<512, blk, 0, stream>>>(tt, Wk, bk, rhat, mh);
  // 4) y_b = Wq^T @ m̂_b ; cb_b = bq . m̂_b   (q GEMM eliminated)
  ypart_kernel<<<dim3(2, 8), blk, 0, stream>>>(Wq, mh, yp);
  yred_kernel<<<dim3(2, B_), blk, 0, stream>>>(yp, y);
  cb_kernel<<<1, blk, 0, stream>>>(bq, mh, cb);
  // 5) u[row] = (img_row . y_b + cb_b) * scl
  u_kernel<<<(B_ * IB_) / 4, blk, 0, stream>>>(img, y, cb, scl, u);
  // 6) textT (B,D,S) f16 — PV GEMM operand
  transpose_text<<<dim3(S_/64, D_/32, B_), blk, 0, stream>>>(text, textT);
  // 7) P = softmax_s( u*Acs + bb2s ) : (B*IB, S) f16
  p_kernel<<<B_ * IB_, blk, 0, stream>>>(u, Acs, bb2s, P);
  // 8) pt_b = P_b @ text_b : (IB, D) x B, two-stage split-K=8, f16 partials
  gemm_bt<<<dim3(D_/128, IB_/128, B_*KS), blk, 0, stream>>>(
      P, textT, nullptr, parts16, IB_, D_, S_, S_, S_, KS,
      IS, DS, ID, nullptr, nullptr, 1.f);
  // 9) reduce 8 slices -> pt16 f16
  reduce_ks8_f16<<<1024, blk, 0, stream>>>(
      (const f16x8*)parts16, (f16x8*)pt16, (unsigned)((B_ * ID) / 8));
  // 10) Wv -> f16
  cvt_f32_to_f16<<<(D_*D_)/1024, blk, 0, stream>>>(Wv, wv16, D_*D_);
  // 11) out = pt @ Wv^T + bv : (B*IB, D) f32 -> d_out  (softmax rows sum
  //     to 1, so P @ bv-broadcast == bv exactly)
  gemm_bt<<<dim3(D_/128, (B_*IB_)/128, 1), blk, 0, stream>>>(
      pt16, wv16, outp, nullptr, B_*IB_, D_, D_, D_, D_, 1,
      0, 0, 0, nullptr, bv, 1.f);
}

// Round 8
// 217.120 us; speedup vs baseline: 3.1652x; 1.1498x over previous
//
#include <hip/hip_runtime.h>

#define B_  8
#define IB_ 1024
#define S_  4096
#define D_  512

typedef _Float16 f16;
typedef _Float16 f16x8 __attribute__((ext_vector_type(8)));
typedef _Float16 f16x4 __attribute__((ext_vector_type(4)));
typedef float    f32x4 __attribute__((ext_vector_type(4)));

// ---------------- async global->LDS, 16B per lane ----------------
__device__ __forceinline__ void gld_lds16(const f16* g, f16* l) {
  __builtin_amdgcn_global_load_lds(
      (const __attribute__((address_space(1))) void*)g,
      (__attribute__((address_space(3))) void*)l, 16, 0, 0);
}

// ---------------- generic C = A(M,K) * B(N,K)^T  (f16 in, f32 accum) -------
// PROVEN r2-r7. 128x128 tile, BK=32, 4 waves, 2-phase prefetch (dbuf LDS,
// counted vmcnt). ksplit>1: grid.z = batch*ksplit, slice stores partials
// (f32 via C32 or f16 via C16) to C + blockIdx.z*sCb; reducer sums slices.
__global__ __launch_bounds__(256) void gemm_bt(
    const f16* __restrict__ A, const f16* __restrict__ B,
    float* __restrict__ C32, f16* __restrict__ C16,
    int M, int N, int K, int lda, int ldb, int ksplit,
    long long sAb, long long sBb, long long sCb,
    const float* __restrict__ bias_row, const float* __restrict__ bias_col,
    float scale)
{
  __shared__ f16 ldsA[2][128 * 32];
  __shared__ f16 ldsB[2][128 * 32];
  const int tid  = threadIdx.x;
  const int lane = tid & 63;
  const int wave = tid >> 6;
  const int zb   = blockIdx.z / ksplit;
  const int ks   = blockIdx.z % ksplit;
  A += (size_t)zb * (size_t)sAb;
  B += (size_t)zb * (size_t)sBb;
  const int m0 = blockIdx.y * 128;
  const int n0 = blockIdx.x * 128;
  const int wm = wave >> 1, wn = wave & 1;

  f32x4 acc[4][4];
#pragma unroll
  for (int i = 0; i < 4; ++i)
#pragma unroll
    for (int j = 0; j < 4; ++j) acc[i][j] = (f32x4){0.f, 0.f, 0.f, 0.f};

  int aoff[4], boff[4];
  const int cl = lane >> 4;
#pragma unroll
  for (int r = 0; r < 4; ++r) {
    int rowa = wm * 64 + r * 16 + (lane & 15);
    aoff[r] = rowa * 32 + (cl ^ ((rowa >> 1) & 3)) * 8;
    int rowb = wn * 64 + r * 16 + (lane & 15);
    boff[r] = rowb * 32 + (cl ^ ((rowb >> 1) & 3)) * 8;
  }
  int srow[2], scg[2];
#pragma unroll
  for (int it = 0; it < 2; ++it) {
    int ch = wave * 64 + it * 256 + lane;
    srow[it] = ch >> 2;
    scg[it]  = (ch & 3) ^ ((srow[it] >> 1) & 3);
  }

#define STAGE(bf_, k0_)                                                        \
  do {                                                                         \
    _Pragma("unroll")                                                          \
    for (int it = 0; it < 2; ++it) {                                           \
      gld_lds16(A + (size_t)(m0 + srow[it]) * (size_t)lda +                    \
                    ((k0_) + scg[it] * 8),                                     \
                &ldsA[bf_][(wave * 64 + it * 256) * 8]);                       \
      gld_lds16(B + (size_t)(n0 + srow[it]) * (size_t)ldb +                    \
                    ((k0_) + scg[it] * 8),                                     \
                &ldsB[bf_][(wave * 64 + it * 256) * 8]);                       \
    }                                                                          \
  } while (0)

  const int Kc   = K / ksplit;
  const int kbeg = ks * Kc;
  const int nt   = Kc / 32;

  STAGE(0, kbeg);
  for (int t = 0; t < nt; ++t) {
    const int cur = t & 1;
    if (t + 1 < nt) {
      STAGE(cur ^ 1, kbeg + (t + 1) * 32);
      asm volatile("s_waitcnt vmcnt(4)" ::: "memory");
    } else {
      asm volatile("s_waitcnt vmcnt(0)" ::: "memory");
    }
    __builtin_amdgcn_s_barrier();
    __builtin_amdgcn_sched_barrier(0);
    f16x8 af[4], bf[4];
#pragma unroll
    for (int r = 0; r < 4; ++r) af[r] = *(const f16x8*)&ldsA[cur][aoff[r]];
#pragma unroll
    for (int r = 0; r < 4; ++r) bf[r] = *(const f16x8*)&ldsB[cur][boff[r]];
#pragma unroll
    for (int mr = 0; mr < 4; ++mr)
#pragma unroll
      for (int nr = 0; nr < 4; ++nr)
        acc[mr][nr] = __builtin_amdgcn_mfma_f32_16x16x32_f16(
            af[mr], bf[nr], acc[mr][nr], 0, 0, 0);
    __builtin_amdgcn_sched_barrier(0);
    __builtin_amdgcn_s_barrier();
    __builtin_amdgcn_sched_barrier(0);
  }
#undef STAGE

  const size_t cz = (ksplit > 1) ? (size_t)blockIdx.z : (size_t)zb;
  float* c32 = C32 ? C32 + cz * (size_t)sCb : nullptr;
  f16*   c16 = C16 ? C16 + cz * (size_t)sCb : nullptr;
#pragma unroll
  for (int mr = 0; mr < 4; ++mr) {
#pragma unroll
    for (int r = 0; r < 4; ++r) {
      int grow = m0 + wm * 64 + mr * 16 + (lane >> 4) * 4 + r;
      float brv = bias_row ? bias_row[grow] : 0.f;
#pragma unroll
      for (int nr = 0; nr < 4; ++nr) {
        int gcol = n0 + wn * 64 + nr * 16 + (lane & 15);
        float v = acc[mr][nr][r] * scale + brv +
                  (bias_col ? bias_col[gcol] : 0.f);
        if (c32) c32[(size_t)grow * N + gcol] = v;
        else     c16[(size_t)grow * N + gcol] = (f16)v;
      }
    }
  }
}

// ---------------- fused-P GEMM: pt = softmax-rank1(A) @ textT^T ------------
// A-operand synthesized in-register: P[i,k] = exp(u_i*Acs[k]+bb2s[k])*inv2_i.
// B = textT (B,D,S). Split-K=4, f16 partial slices [zb][4][IB*D].
// 1-D grid 1024, bijective XCD-chunked swizzle (8 m-blocks sharing a B-slab
// land on one XCD). LDS: B dbuf 16KB + const slice 8KB.
__global__ __launch_bounds__(256) void gemm_pt(
    const f16* __restrict__ Bt, const float* __restrict__ uarr,
    const float* __restrict__ inv2, const float* __restrict__ Acs,
    const float* __restrict__ bb2s, f16* __restrict__ parts)
{
  __shared__ f16 ldsB[2][128 * 32];
  __shared__ float cA[1024], cB[1024];     // const slice, Kc=1024
  const int tid  = threadIdx.x;
  const int lane = tid & 63;
  const int wave = tid >> 6;
  // swizzle: 1024 blocks -> 128 contiguous per XCD
  int id = (int)blockIdx.x;
  id = (id & 7) * 128 + (id >> 3);
  const int x  = id & 3;          // n-tile
  const int y  = (id >> 2) & 7;   // m-tile
  const int z  = id >> 5;         // zb*4 + ks
  const int zb = z >> 2, ks = z & 3;
  const int kbeg = ks * 1024;
  const int m0 = y * 128, n0 = x * 128;
  const int wm = wave >> 1, wn = wave & 1;
  const f16* B = Bt + (size_t)zb * ((size_t)D_ * S_);

  for (int i = tid; i < 1024; i += 256) {
    cA[i] = Acs[kbeg + i];
    cB[i] = bb2s[kbeg + i];
  }
  const int cl = lane >> 4;
  float u_[4], iv_[4];
#pragma unroll
  for (int r = 0; r < 4; ++r) {
    int row = zb * IB_ + m0 + wm * 64 + r * 16 + (lane & 15);
    u_[r]  = uarr[row];
    iv_[r] = inv2[row];
  }
  int boff[4];
#pragma unroll
  for (int r = 0; r < 4; ++r) {
    int rowb = wn * 64 + r * 16 + (lane & 15);
    boff[r] = rowb * 32 + (cl ^ ((rowb >> 1) & 3)) * 8;
  }
  int srow[2], scg[2];
#pragma unroll
  for (int it = 0; it < 2; ++it) {
    int ch = wave * 64 + it * 256 + lane;
    srow[it] = ch >> 2;
    scg[it]  = (ch & 3) ^ ((srow[it] >> 1) & 3);
  }
  f32x4 acc[4][4];
#pragma unroll
  for (int i = 0; i < 4; ++i)
#pragma unroll
    for (int j = 0; j < 4; ++j) acc[i][j] = (f32x4){0.f, 0.f, 0.f, 0.f};

#define STAGEB(bf_, k0_)                                                       \
  do {                                                                         \
    _Pragma("unroll")                                                          \
    for (int it = 0; it < 2; ++it) {                                           \
      gld_lds16(B + (size_t)(n0 + srow[it]) * (size_t)S_ +                     \
                    ((k0_) + scg[it] * 8),                                     \
                &ldsB[bf_][(wave * 64 + it * 256) * 8]);                       \
    }                                                                          \
  } while (0)

  __syncthreads();                 // const fill visible
  STAGEB(0, kbeg);
  for (int t = 0; t < 32; ++t) {
    const int cur = t & 1;
    if (t + 1 < 32) STAGEB(cur ^ 1, kbeg + (t + 1) * 32);
    // synthesize A fragments (VALU/trans work hides the B-load latency)
    const int kl = t * 32 + cl * 8;
    float a8[8], b8[8];
#pragma unroll
    for (int j = 0; j < 8; ++j) { a8[j] = cA[kl + j]; b8[j] = cB[kl + j]; }
    f16x8 af[4];
#pragma unroll
    for (int r = 0; r < 4; ++r)
#pragma unroll
      for (int j = 0; j < 8; ++j)
        af[r][j] = (f16)(__expf(fmaf(u_[r], a8[j], b8[j])) * iv_[r]);
    if (t + 1 < 32) asm volatile("s_waitcnt vmcnt(2)" ::: "memory");
    else            asm volatile("s_waitcnt vmcnt(0)" ::: "memory");
    __builtin_amdgcn_s_barrier();
    __builtin_amdgcn_sched_barrier(0);
    f16x8 bf[4];
#pragma unroll
    for (int r = 0; r < 4; ++r) bf[r] = *(const f16x8*)&ldsB[cur][boff[r]];
#pragma unroll
    for (int mr = 0; mr < 4; ++mr)
#pragma unroll
      for (int nr = 0; nr < 4; ++nr)
        acc[mr][nr] = __builtin_amdgcn_mfma_f32_16x16x32_f16(
            af[mr], bf[nr], acc[mr][nr], 0, 0, 0);
    __builtin_amdgcn_sched_barrier(0);
    __builtin_amdgcn_s_barrier();
    __builtin_amdgcn_sched_barrier(0);
  }
#undef STAGEB

  f16* cp = parts + (size_t)z * (size_t)(IB_ * D_);
#pragma unroll
  for (int mr = 0; mr < 4; ++mr) {
#pragma unroll
    for (int rr = 0; rr < 4; ++rr) {
      int grow = m0 + wm * 64 + mr * 16 + (lane >> 4) * 4 + rr;
#pragma unroll
      for (int nr = 0; nr < 4; ++nr) {
        int gcol = n0 + wn * 64 + nr * 16 + (lane & 15);
        cp[(size_t)grow * D_ + gcol] = (f16)acc[mr][nr][rr];
      }
    }
  }
}

// ---------------- reduce 4 f16 split-K slices: [B][4][ID] -> [B][ID] ------
__global__ __launch_bounds__(256) void reduce_ks4_f16(
    const f16x8* __restrict__ p, f16x8* __restrict__ o, unsigned n8)
{
  const unsigned pb8 = (IB_ * D_) / 8;   // 65536 f16x8 units per slice
  unsigned i = blockIdx.x * 256u + threadIdx.x;
  const unsigned stride = gridDim.x * 256u;
  for (; i < n8; i += stride) {
    unsigned g = i / pb8, r = i - g * pb8;
    size_t base = ((size_t)g * 4u) * pb8 + r;
    float acc[8] = {0.f, 0.f, 0.f, 0.f, 0.f, 0.f, 0.f, 0.f};
#pragma unroll
    for (int ks = 0; ks < 4; ++ks) {
      f16x8 v = p[base + (size_t)ks * pb8];
#pragma unroll
      for (int j = 0; j < 8; ++j) acc[j] += (float)v[j];
    }
    f16x8 h;
#pragma unroll
    for (int j = 0; j < 8; ++j) h[j] = (f16)acc[j];
    o[i] = h;
  }
}

// ---------------- reduce 2 f16 slices + col bias -> f32 out ---------------
__global__ __launch_bounds__(256) void reduce_ks2_bias(
    const f16x8* __restrict__ p, const float* __restrict__ bias,
    float4* __restrict__ o, unsigned n8)
{
  unsigned i = blockIdx.x * 256u + threadIdx.x;
  const unsigned stride = gridDim.x * 256u;
  for (; i < n8; i += stride) {
    f16x8 a = p[i];
    f16x8 b = p[i + (size_t)n8];
    const int c0 = (int)((i * 8u) & (D_ - 1));
    float4 lo, hi;
    lo.x = (float)a[0] + (float)b[0] + bias[c0 + 0];
    lo.y = (float)a[1] + (float)b[1] + bias[c0 + 1];
    lo.z = (float)a[2] + (float)b[2] + bias[c0 + 2];
    lo.w = (float)a[3] + (float)b[3] + bias[c0 + 3];
    hi.x = (float)a[4] + (float)b[4] + bias[c0 + 4];
    hi.y = (float)a[5] + (float)b[5] + bias[c0 + 5];
    hi.z = (float)a[6] + (float)b[6] + bias[c0 + 6];
    hi.w = (float)a[7] + (float)b[7] + bias[c0 + 7];
    o[(size_t)i * 2]     = lo;
    o[(size_t)i * 2 + 1] = hi;
  }
}

// ---------------- f32 -> f16 ----------------
__global__ __launch_bounds__(256) void cvt_f32_to_f16(
    const float* __restrict__ in, f16* __restrict__ out, unsigned n)
{
  unsigned i = (blockIdx.x * 256u + threadIdx.x) * 4u;
  if (i >= n) return;
  const float4 v = *(const float4*)(in + i);
  f16x4 h;
  h[0] = (f16)v.x; h[1] = (f16)v.y; h[2] = (f16)v.z; h[3] = (f16)v.w;
  *(f16x4*)(out + i) = h;
}

// ---------------- text (B,S,D) f32 -> textT (B,D,S) f16 ------------------
__global__ __launch_bounds__(256) void transpose_text(
    const float* __restrict__ in, f16* __restrict__ out)
{
  __shared__ float t[32][65];
  const int b = blockIdx.z;
  const int s0 = blockIdx.x * 64, d0 = blockIdx.y * 32;
  const int dx = threadIdx.x & 31;
  const int sy = threadIdx.x >> 5;
  const float* ip = in + ((size_t)b * S_ + s0) * D_ + d0;
#pragma unroll
  for (int j = 0; j < 8; ++j) {
    int sl = j * 8 + sy;
    t[dx][sl] = ip[(size_t)sl * D_ + dx];
  }
  __syncthreads();
  const int sx = threadIdx.x & 63;
  const int dy = threadIdx.x >> 6;
  f16* op = out + ((size_t)b * D_ + d0) * S_ + s0;
#pragma unroll
  for (int j = 0; j < 8; ++j) {
    int dl = j * 4 + dy;
    op[(size_t)dl * S_ + sx] = (f16)t[dl][sx];
  }
}

// ---------------- row sums of Wb2s (S, IB): Acs[s] = sum_j W[s,j] --------
__global__ __launch_bounds__(256) void rowsum_kernel(
    const float* __restrict__ W, float* __restrict__ out)
{
  int s = blockIdx.x;
  const float* row = W + (size_t)s * IB_;
  float acc = 0.f;
  for (int j = threadIdx.x; j < IB_; j += 256) acc += row[j];
  __shared__ float red[4];
#pragma unroll
  for (int o = 32; o >= 1; o >>= 1) acc += __shfl_xor(acc, o);
  if ((threadIdx.x & 63) == 0) red[threadIdx.x >> 6] = acc;
  __syncthreads();
  if (threadIdx.x == 0) out[s] = red[0] + red[1] + red[2] + red[3];
}

// ---------------- mu = alpha*Acs + bb2s, top-2050 mask, r̂ -----------------
__device__ __forceinline__ unsigned fkey(float x) {
  unsigned u = __float_as_uint(x);
  return (u & 0x80000000u) ? ~u : (u | 0x80000000u);
}

__global__ __launch_bounds__(256) void prep_mu(
    const float* __restrict__ Acs, const float* __restrict__ bb2s,
    float* __restrict__ muk, float* __restrict__ rhat)
{
  __shared__ float vals[S_];
  __shared__ unsigned hist[256];
  __shared__ unsigned sprefix;
  __shared__ int srem;
  __shared__ float rred[4];
  const float e1 = 2.71828182845904523536f;
  const float Z = 3.f * e1 + (float)(IB_ - 3);   // interior-row normalizer
  const float alpha = 1.f / Z;
  for (int s = threadIdx.x; s < S_; s += 256)
    vals[s] = alpha * Acs[s] + bb2s[s];
  if (threadIdx.x == 0) { sprefix = 0u; srem = S_ / 2 + 2; }  // 2050
  __syncthreads();
  for (int shift = 24; shift >= 0; shift -= 8) {
    hist[threadIdx.x] = 0u;
    __syncthreads();
    unsigned pfx = sprefix;
    unsigned himask = (shift == 24) ? 0u : (0xFFFFFFFFu << (shift + 8));
    for (int s = threadIdx.x; s < S_; s += 256) {
      unsigned key = fkey(vals[s]);
      if ((key & himask) == (pfx & himask))
        atomicAdd(&hist[(key >> shift) & 255u], 1u);
    }
    __syncthreads();
    if (threadIdx.x == 0) {
      int rem = srem;
      unsigned acc = 0;
      int b = 255;
      for (; b > 0; --b) {
        unsigned c = hist[b];
        if (acc + c >= (unsigned)rem) break;
        acc += c;
      }
      sprefix = pfx | ((unsigned)b << shift);
      srem = rem - (int)acc;
    }
    __syncthreads();
  }
  const unsigned T = sprefix;
  float myrs = 0.f;
  for (int s = threadIdx.x; s < S_; s += 256) {
    float v = vals[s];
    bool keep = fkey(v) >= T;
    muk[s] = keep ? v : 0.f;
    if (keep) myrs += v;
  }
#pragma unroll
  for (int o = 32; o >= 1; o >>= 1) myrs += __shfl_xor(myrs, o);
  if ((threadIdx.x & 63) == 0) rred[threadIdx.x >> 6] = myrs;
  __syncthreads();
  if (threadIdx.x == 0) rhat[0] = rred[0] + rred[1] + rred[2] + rred[3];
}

// ---------------- t̂ partials: tp[b][c][d] = sum_{s in chunk c} muk[s]*text -
__global__ __launch_bounds__(256) void that_partial(
    const float* __restrict__ text, const float* __restrict__ muk,
    float* __restrict__ tp)
{
  const int d = blockIdx.x * 256 + threadIdx.x;   // gridDim.x = 2
  const int c = blockIdx.y;                        // 32 chunks of 128 rows
  const int b = blockIdx.z;
  const float* tb = text + ((size_t)b * S_ + (size_t)c * 128) * D_ + d;
  float acc = 0.f;
  for (int s = 0; s < 128; ++s) {
    float m = muk[c * 128 + s];        // wave-uniform -> skips whole row load
    if (m != 0.f) acc += m * tb[(size_t)s * D_];
  }
  tp[((size_t)b * 32 + c) * D_ + d] = acc;
}

// ---------------- tt[b][d] = sum_c tp[b][c][d] ---------------------------
__global__ __launch_bounds__(256) void tt_reduce(
    const float* __restrict__ tp, float* __restrict__ tt)
{
  const int d = blockIdx.x * 256 + threadIdx.x;   // gridDim.x = 2
  const int b = blockIdx.y;                        // gridDim.y = 8
  float acc = 0.f;
#pragma unroll
  for (int c = 0; c < 32; ++c) acc += tp[((size_t)b * 32 + c) * D_ + d];
  tt[(size_t)b * D_ + d] = acc;
}

// ---------------- m̂[b][r] = Wk[r,:].tt[b] + bk[r]*r̂ ; grid = 512 rows ----
__global__ __launch_bounds__(256) void mhat2_kernel(
    const float* __restrict__ tt, const float* __restrict__ Wk,
    const float* __restrict__ bk, const float* __restrict__ rhat,
    float* __restrict__ mh)
{
  __shared__ float tl[B_ * D_];        // 16 KB: all batches' t̂
  const int t = threadIdx.x;
  for (int i = t; i < B_ * D_; i += 256) tl[i] = tt[i];
  __syncthreads();
  const int r = blockIdx.x;
  const int lane = t & 63, wave = t >> 6;
  const float* wr = Wk + (size_t)r * D_;
  float w[8];
#pragma unroll
  for (int j = 0; j < 8; ++j) w[j] = wr[lane + 64 * j];
  const float bkr = bk[r] * rhat[0];
#pragma unroll
  for (int bb = 0; bb < 2; ++bb) {
    const int b = wave * 2 + bb;
    float acc = 0.f;
#pragma unroll
    for (int j = 0; j < 8; ++j) acc += w[j] * tl[b * D_ + lane + 64 * j];
#pragma unroll
    for (int o = 32; o >= 1; o >>= 1) acc += __shfl_xor(acc, o);
    if (lane == 0) mh[b * D_ + r] = acc + bkr;
  }
}

// ---------------- ypart[c][b][d] = sum_{r in chunk c} Wq[r,d]*mh[b][r] ----
__global__ __launch_bounds__(256) void ypart_kernel(
    const float* __restrict__ Wq, const float* __restrict__ mh,
    float* __restrict__ yp)
{
  __shared__ float ms[B_ * 64];        // mh slice: 8 batches x 64 rows
  const int t = threadIdx.x;
  const int d = blockIdx.x * 256 + t;  // gridDim.x = 2
  const int c = blockIdx.y;            // gridDim.y = 8 chunks of 64 rows
  for (int i = t; i < B_ * 64; i += 256) {
    int b = i >> 6, rr = i & 63;
    ms[i] = mh[b * D_ + c * 64 + rr];
  }
  __syncthreads();
  float acc[8] = {0.f, 0.f, 0.f, 0.f, 0.f, 0.f, 0.f, 0.f};
  for (int rr = 0; rr < 64; ++rr) {
    float wv = Wq[(size_t)(c * 64 + rr) * D_ + d];
#pragma unroll
    for (int b = 0; b < 8; ++b) acc[b] += wv * ms[b * 64 + rr];
  }
#pragma unroll
  for (int b = 0; b < 8; ++b)
    yp[((size_t)c * 8 + b) * D_ + d] = acc[b];
}

// ---------------- y[b][d] = sum_c ypart[c][b][d] -------------------------
__global__ __launch_bounds__(256) void yred_kernel(
    const float* __restrict__ yp, float* __restrict__ y)
{
  const int d = blockIdx.x * 256 + threadIdx.x;   // gridDim.x = 2
  const int b = blockIdx.y;                        // gridDim.y = 8
  float acc = 0.f;
#pragma unroll
  for (int c = 0; c < 8; ++c) acc += yp[((size_t)c * 8 + b) * D_ + d];
  y[(size_t)b * D_ + d] = acc;
}

// ---------------- cb[b] = bq . mh[b] -------------------------------------
__global__ __launch_bounds__(256) void cb_kernel(
    const float* __restrict__ bq, const float* __restrict__ mh,
    float* __restrict__ cb)
{
  const int lane = threadIdx.x & 63, wave = threadIdx.x >> 6;
#pragma unroll
  for (int bb = 0; bb < 2; ++bb) {
    const int b = wave * 2 + bb;
    float acc = 0.f;
#pragma unroll
    for (int j = 0; j < 8; ++j) {
      int k = lane + 64 * j;
      acc += bq[k] * mh[b * D_ + k];
    }
#pragma unroll
    for (int o = 32; o >= 1; o >>= 1) acc += __shfl_xor(acc, o);
    if (lane == 0) cb[b] = acc;
  }
}

// ---------------- u[row] = (img_row . y_b + cb[b]) * scl ------------------
__global__ __launch_bounds__(256) void u_kernel(
    const float* __restrict__ img, const float* __restrict__ y,
    const float* __restrict__ cb, float scl, float* __restrict__ u)
{
  const int lane = threadIdx.x & 63, wave = threadIdx.x >> 6;
  const int row = blockIdx.x * 4 + wave;          // grid = 2048
  const int b = row >> 10;
  const float* ir = img + (size_t)row * D_;
  const float* yb = y + (size_t)b * D_;
  float acc = 0.f;
#pragma unroll
  for (int j = 0; j < 8; ++j) {
    int d = lane + 64 * j;
    acc += ir[d] * yb[d];
  }
#pragma unroll
  for (int o = 32; o >= 1; o >>= 1) acc += __shfl_xor(acc, o);
  if (lane == 0) u[row] = (acc + cb[b]) * scl;
}

// ---------------- per-row softmax stats: inv2[row] = exp(-mx)/Z -----------
__global__ __launch_bounds__(256) void pstat_kernel(
    const float* __restrict__ uarr, const float* __restrict__ Acs,
    const float* __restrict__ bb2s, float* __restrict__ inv2)
{
  const int row = blockIdx.x;
  const int t = threadIdx.x;
  __shared__ float red[4];
  const float u = uarr[row];
  float v[16];
  float mx = -3.4e38f;
#pragma unroll
  for (int j = 0; j < 16; ++j) {
    int s = t + 256 * j;
    v[j] = fmaf(u, Acs[s], bb2s[s]);
    mx = fmaxf(mx, v[j]);
  }
#pragma unroll
  for (int o = 32; o >= 1; o >>= 1) mx = fmaxf(mx, __shfl_xor(mx, o));
  if ((t & 63) == 0) red[t >> 6] = mx;
  __syncthreads();
  mx = fmaxf(fmaxf(red[0], red[1]), fmaxf(red[2], red[3]));
  __syncthreads();
  float sum = 0.f;
#pragma unroll
  for (int j = 0; j < 16; ++j) sum += __expf(v[j] - mx);
#pragma unroll
  for (int o = 32; o >= 1; o >>= 1) sum += __shfl_xor(sum, o);
  if ((t & 63) == 0) red[t >> 6] = sum;
  __syncthreads();
  if (t == 0) {
    float Zs = red[0] + red[1] + red[2] + red[3];
    inv2[row] = __expf(-mx) / Zs;
  }
}

// =========================================================================
extern "C" void kernel_launch(void* const* d_in, const int* in_sizes, int n_in,
                              void* d_out, int out_size, void* d_ws, size_t ws_size,
                              hipStream_t stream)
{
  const float* text = (const float*)d_in[0];   // (B,S,D)
  const float* img  = (const float*)d_in[1];   // (B,IB,D)
  const float* Wq   = (const float*)d_in[2];
  const float* bq   = (const float*)d_in[3];
  const float* Wk   = (const float*)d_in[4];
  const float* bk   = (const float*)d_in[5];
  const float* Wv   = (const float*)d_in[6];
  const float* bv   = (const float*)d_in[7];
  const float* Wb2s = (const float*)d_in[8];   // (S,IB)
  const float* bb2s = (const float*)d_in[9];   // (S,)
  float* outp = (float*)d_out;
  char* ws = (char*)d_ws;

  const long long ID = (long long)IB_ * D_;    // 2^19
  const size_t MB = 1048576ull;

  // ws layout (NEED = 96 MiB; >=200 MiB proved available in round 2):
  //  [  0, 32)  textT f16 (B,D,S)
  //  [ 32, 40)  pt16 f16
  //  [ 40, 72)  parts_pt f16, 4 slices x 8 MB
  //  [ 72, 88)  parts_out f16, 2 slices x 8 MB
  //  [ 88, 89)  wv16
  //  [ 89, ..)  smalls
  const size_t NEED = 96 * MB;
  if (ws_size < NEED) return;

  f16*   textT   = (f16*)(ws + 0);
  f16*   pt16    = (f16*)(ws + 32 * MB);
  f16*   partsPT = (f16*)(ws + 40 * MB);
  f16*   partsO  = (f16*)(ws + 72 * MB);
  f16*   wv16    = (f16*)(ws + 88 * MB);
  const size_t SB = 89 * MB;
  float* Acs  = (float*)(ws + SB);
  float* muk  = (float*)(ws + SB + 16384);
  float* tp   = (float*)(ws + SB + 32768);        // 512 KB
  float* tt   = (float*)(ws + SB + 557056);
  float* mh   = (float*)(ws + SB + 573440);
  float* rhat = (float*)(ws + SB + 589824);
  float* yp   = (float*)(ws + SB + 593920);       // 128 KB
  float* y    = (float*)(ws + SB + 724992);
  float* cb   = (float*)(ws + SB + 741376);
  float* u    = (float*)(ws + SB + 745472);       // 32 KB
  float* inv2 = (float*)(ws + SB + 778240);       // 32 KB

  dim3 blk(256);
  const float scl = 0.04419417382415922f;  // 1/sqrt(512)

  // 1) Acs = rowsum(Wb2s); mu + top-2050 mask + r̂
  rowsum_kernel<<<S_, blk, 0, stream>>>(Wb2s, Acs);
  prep_mu<<<1, blk, 0, stream>>>(Acs, bb2s, muk, rhat);
  // 2) t̂ = muk-weighted row-sum of text
  that_partial<<<dim3(2, 32, B_), blk, 0, stream>>>(text, muk, tp);
  tt_reduce<<<dim3(2, B_), blk, 0, stream>>>(tp, tt);
  // 3) m̂_b = Wk @ t̂_b + bk*r̂
  mhat2_kernel<<<512, blk, 0, stream>>>(tt, Wk, bk, rhat, mh);
  // 4) y_b = Wq^T @ m̂_b ; cb_b = bq . m̂_b
  ypart_kernel<<<dim3(2, 8), blk, 0, stream>>>(Wq, mh, yp);
  yred_kernel<<<dim3(2, B_), blk, 0, stream>>>(yp, y);
  cb_kernel<<<1, blk, 0, stream>>>(bq, mh, cb);
  // 5) u[row] = (img_row . y_b + cb_b) * scl
  u_kernel<<<(B_ * IB_) / 4, blk, 0, stream>>>(img, y, cb, scl, u);
  // 6) per-row softmax stats (P itself is never materialized)
  pstat_kernel<<<B_ * IB_, blk, 0, stream>>>(u, Acs, bb2s, inv2);
  // 7) textT (B,D,S) f16 — PV GEMM operand
  transpose_text<<<dim3(S_/64, D_/32, B_), blk, 0, stream>>>(text, textT);
  // 8) pt_b = P_b @ text_b with P synthesized in-register; split-K=4
  gemm_pt<<<1024, blk, 0, stream>>>(textT, u, inv2, Acs, bb2s, partsPT);
  // 9) reduce 4 slices -> pt16 f16
  reduce_ks4_f16<<<1024, blk, 0, stream>>>(
      (const f16x8*)partsPT, (f16x8*)pt16, (unsigned)((B_ * ID) / 8));
  // 10) Wv -> f16
  cvt_f32_to_f16<<<(D_*D_)/1024, blk, 0, stream>>>(Wv, wv16, D_*D_);
  // 11) out = pt @ Wv^T (+bv at reduce) : split-K=2, f16 partials
  gemm_bt<<<dim3(D_/128, (B_*IB_)/128, 2), blk, 0, stream>>>(
      pt16, wv16, nullptr, partsO, B_*IB_, D_, D_, D_, D_, 2,
      0, 0, (long long)B_ * ID, nullptr, nullptr, 1.f);
  // 12) reduce 2 slices + bv -> d_out f32 (softmax rows sum to 1, so
  //     P @ bv-broadcast == bv exactly)
  reduce_ks2_bias<<<1024, blk, 0, stream>>>(
      (const f16x8*)partsO, bv, (float4*)outp, (unsigned)((B_ * ID) / 8));
}